// Round 14
// baseline (607.393 us; speedup 1.0000x reference)
//
#include <hip/hip_runtime.h>
#include <hip/hip_bf16.h>

// Problem constants (B,S,N,F,H,E) = (4,8,4000,64,128,32000)
#define B_  4
#define S_  8
#define N_  4000
#define F_  64
#define H_  128
#define E_  32000
#define G_  (B_*S_)        // 32 graphs
#define GN_ (G_*N_)        // 128000 node rows
#define M_  (B_*N_)        // 16000 LSTM rows
#define GE_ (G_*E_)        // 1,024,000 edges total
#define NBLK_   8          // hist/fill blocks per graph
#define EPB_    (E_/NBLK_) // 4000 edges per block

// f32 weight scratch offsets (floats)
#define OFF_W0S 0
#define OFF_B0S 8192
#define OFF_W0D 8320
#define OFF_B0D 16512
#define OFF_W1S 16640
#define OFF_B1S 33024
#define OFF_W1D 33152
#define OFF_B1D 49536
#define OFF_WIH 49664
#define OFF_WHH 115200
#define OFF_BIH 180736
#define OFF_BHH 181248
#define OFF_WP  181760
#define OFF_BP  189952
#define WCV_TOTAL 190016

// workspace layout (float offsets)
#define WS_FLAG   0
#define WS_WCV    16
#define WS_WPH    190032      // Whh bf16 [512][128]: 65536 ushorts
#define WS_WPC    222800      // composed Wc bf16 [512][256]: 131072 ushorts
#define WS_BIASC  288336      // 512 f32
#define WS_DEGO   288848      // deg_o, deg_i, cnt_i, cnt_o contiguous: 4 x 128000 words
#define WS_DEGI   416848
#define WS_CNTI   544848
#define WS_CNTO   672848
#define WS_RPI    800848      // 32*4001
#define WS_RPO    928880
#define WS_CSRI   1312912     // int2 x GE
#define WS_CSRO   3360912
#define WS_X2     5408912     // Xb [GN][64] bf16 (16.4M ushorts)
#define WS_PART   9608912     // hist partials 4 x [32][8][4000] words = 4,096,000 floats
#define WS_HB     21792912    // [GN][128] bf16
#define WS_WC0    46368912    // Wc0 bf16 [128][128]: 16384 ushorts = 8192 floats
// end: 46,377,104 floats = 185.5 MiB (proven budget >= 193 MiB)

typedef __attribute__((ext_vector_type(8))) short bf16x8;
typedef __attribute__((ext_vector_type(4))) float f32x4;
typedef __attribute__((ext_vector_type(8))) unsigned short ushort8;

__device__ inline float bfu2f(unsigned short u){ union{unsigned int i; float f;} v; v.i=((unsigned int)u)<<16; return v.f; }
__device__ inline unsigned short f2bfu(float f){ __hip_bfloat16 b = __float2bfloat16(f); return *(unsigned short*)&b; }
__device__ inline float rcpf(float x){ return __builtin_amdgcn_rcpf(x); }
__device__ inline float sigmf(float x){ return rcpf(1.0f + __expf(-x)); }
__device__ inline float tanhfast(float x){ return 1.0f - 2.0f*rcpf(1.0f + __expf(2.0f*x)); }
__device__ inline float loadf(const void* p, long i, int isf32){
    return isf32 ? ((const float*)p)[i]
                 : __bfloat162float(((const __hip_bfloat16*)p)[i]);
}
__device__ inline float4 cvtbf4(ushort4 u){
    float4 f;
    f.x = __uint_as_float(((unsigned)u.x)<<16);
    f.y = __uint_as_float(((unsigned)u.y)<<16);
    f.z = __uint_as_float(((unsigned)u.z)<<16);
    f.w = __uint_as_float(((unsigned)u.w)<<16);
    return f;
}

// ---------------- dtype sniff (inputs f32 vs bf16) ----------------
__global__ void sniff_kernel(const unsigned int* __restrict__ ew, int* __restrict__ flag){
    __shared__ int s;
    if (threadIdx.x == 0) s = 0;
    __syncthreads();
    unsigned int lo = ew[threadIdx.x] & 0xFFFFu;
    if (lo > 0x3F80u) atomicOr(&s, 1);
    __syncthreads();
    if (threadIdx.x == 0) flag[0] = s;   // 1 => inputs are f32
}

// ---------------- weight conversion to f32 scratch ----------------
struct WSeg { const void* src; int base; int n; };
struct WDesc { WSeg seg[14]; };
__global__ void convert_weights(WDesc d, float* __restrict__ dst, const int* __restrict__ flag){
    int isf32 = flag[0];
    int idx = blockIdx.x*256 + threadIdx.x;
    #pragma unroll
    for (int s=0;s<14;s++){
        int off = idx - d.seg[s].base;
        if (off >= 0 && off < d.seg[s].n){
            dst[idx] = loadf(d.seg[s].src, off, isf32);
            return;
        }
    }
}

// ---------------- Whh bf16 copy ----------------
__global__ void repack_whh(const float* __restrict__ wcv, unsigned short* __restrict__ whb){
    int idx = blockIdx.x*256 + threadIdx.x;   // < 65536
    whb[idx] = f2bfu(wcv[OFF_WHH + idx]);
}

// ---------------- layer-0 composed weights: Wc0[n][k] bf16 [128][128] ----------------
__global__ void repack_wc0(const float* __restrict__ wcv, unsigned short* __restrict__ wc0){
    int idx = blockIdx.x*256 + threadIdx.x;   // < 16384
    int k = idx & 127, n = idx >> 7;
    float v = (k < 64) ? 0.5f*wcv[OFF_W0S + n*64 + k] : 0.5f*wcv[OFF_W0D + n*64 + (k-64)];
    wc0[idx] = f2bfu(v);
}

// ---------------- x_seq -> bf16 Xb [GN][64] ----------------
__global__ void xcvt_kernel(const void* __restrict__ x, const int* __restrict__ flag,
                            unsigned short* __restrict__ Xb){
    long idx = (long)blockIdx.x*256 + threadIdx.x;
    if (idx >= (long)GN_*64) return;
    Xb[idx] = f2bfu(loadf(x, idx, flag[0]));
}

// ---------------- composed weights: Wc[n][k] bf16 [512][256] ----------------
__global__ __launch_bounds__(256) void compose_wc(const float* __restrict__ wcv,
                                                  unsigned short* __restrict__ wpc){
    int n = blockIdx.x;        // 512 blocks
    int k = threadIdx.x;       // 256
    const float* wih = wcv + OFF_WIH + n*128;
    const float* w1  = (k < 128) ? (wcv + OFF_W1S + k) : (wcv + OFF_W1D + (k-128));
    float s = 0.f;
    for (int h=0; h<128; h++) s += wih[h] * w1[h*128];
    wpc[n*256 + k] = f2bfu(0.5f * s);
}

// biasc[n] = bih[n]+bhh[n] + sum_h Wih[n][h]*0.5*(b1s[h]+b1d[h])
__global__ void compose_bias(const float* __restrict__ wcv, float* __restrict__ biasc){
    int n = blockIdx.x*256 + threadIdx.x;
    if (n >= 512) return;
    float s = wcv[OFF_BIH+n] + wcv[OFF_BHH+n];
    const float* wih = wcv + OFF_WIH + n*128;
    for (int h=0; h<128; h++) s += wih[h] * 0.5f*(wcv[OFF_B1S+h] + wcv[OFF_B1D+h]);
    biasc[n] = s;
}

// ---------------- histogram: per-(graph, edge-block) LDS partials ----------------
__global__ __launch_bounds__(1024) void hist_kernel(
        const int* __restrict__ ei, const void* __restrict__ ew, const int* __restrict__ flag,
        float* __restrict__ part){
    __shared__ float wdo[N_], wdi[N_];
    __shared__ int   co[N_],  ci[N_];
    int xcd  = blockIdx.x & 7;
    int r2   = blockIdx.x >> 3;
    int g    = xcd*4 + (r2 & 3);
    int b    = r2 >> 2;                     // 0..7
    int tid  = threadIdx.x;
    int isf32 = flag[0];
    for (int i=tid;i<N_;i+=1024){ wdo[i]=0.f; wdi[i]=0.f; co[i]=0; ci[i]=0; }
    __syncthreads();
    const int* eib = ei + g*2*E_;
    int e0 = b*EPB_;
    for (int e=e0+tid; e<e0+EPB_; e+=1024){
        int s = eib[e], d = eib[E_+e];
        float w = loadf(ew, (long)g*E_+e, isf32);
        atomicAdd(&wdo[s], w); atomicAdd(&wdi[d], w);
        atomicAdd(&co[s], 1);  atomicAdd(&ci[d], 1);
    }
    __syncthreads();
    float* Pdo = part + (size_t)(0*G_ + g)*NBLK_*N_ + (size_t)b*N_;
    float* Pdi = part + (size_t)(1*G_ + g)*NBLK_*N_ + (size_t)b*N_;
    int*   Pci = (int*)part + (size_t)(2*G_ + g)*NBLK_*N_ + (size_t)b*N_;
    int*   Pco = (int*)part + (size_t)(3*G_ + g)*NBLK_*N_ + (size_t)b*N_;
    for (int i=tid;i<N_;i+=1024){
        Pdo[i] = wdo[i]; Pdi[i] = wdi[i];
        Pci[i] = ci[i];  Pco[i] = co[i];
    }
}

// ---------------- reduce partials -> deg/cnt; counts -> per-block exclusive prefix ----------------
__global__ __launch_bounds__(256) void reduce_hist(
        float* __restrict__ part,
        float* __restrict__ deg_o, float* __restrict__ deg_i,
        int* __restrict__ cnt_in, int* __restrict__ cnt_out){
    int g = blockIdx.x >> 4;
    int n = (blockIdx.x & 15)*256 + threadIdx.x;
    if (n >= N_) return;
    float* Pdo = part + (size_t)(0*G_ + g)*NBLK_*N_;
    float* Pdi = part + (size_t)(1*G_ + g)*NBLK_*N_;
    int*   Pci = (int*)part + (size_t)(2*G_ + g)*NBLK_*N_;
    int*   Pco = (int*)part + (size_t)(3*G_ + g)*NBLK_*N_;
    float sdo = 0.f, sdi = 0.f;
    int sci = 0, sco = 0;
    #pragma unroll
    for (int b=0;b<NBLK_;b++){
        size_t idx = (size_t)b*N_ + n;
        sdo += Pdo[idx]; sdi += Pdi[idx];
        int vi = Pci[idx], vo = Pco[idx];
        Pci[idx] = sci;  Pco[idx] = sco;   // exclusive prefix for fill
        sci += vi; sco += vo;
    }
    deg_o[g*N_+n] = sdo; deg_i[g*N_+n] = sdi;
    cnt_in[g*N_+n] = sci; cnt_out[g*N_+n] = sco;
}

// ---------------- exclusive scan -> row_ptr ----------------
__global__ __launch_bounds__(256) void scan_kernel(
        const int* __restrict__ cnt_in, const int* __restrict__ cnt_out,
        int* __restrict__ rp_in, int* __restrict__ rp_out){
    __shared__ int part[256], pref[256];
    int g = blockIdx.x & 31, dir = blockIdx.x >> 5;
    const int* cnt = (dir ? cnt_out : cnt_in) + g*N_;
    int* rp  = (dir ? rp_out  : rp_in)  + g*(N_+1);
    int tid = threadIdx.x, base = tid*16;
    int sum = 0;
    for (int i=0;i<16;i++){ int p = base+i; if (p < N_) sum += cnt[p]; }
    part[tid] = sum;
    __syncthreads();
    if (tid == 0){ int run = 0; for (int j=0;j<256;j++){ pref[j] = run; run += part[j]; } }
    __syncthreads();
    int run = pref[tid];
    for (int i=0;i<16;i++){
        int p = base+i;
        if (p < N_){ rp[p] = run; run += cnt[p]; }
    }
    if (tid == 255) rp[N_] = run;
}

// ---------------- fill CSR (no global atomics) ----------------
__global__ __launch_bounds__(1024) void fill_kernel(
        const int* __restrict__ ei, const void* __restrict__ ew,
        const int* __restrict__ flag,
        const float* __restrict__ deg_o, const float* __restrict__ deg_i,
        const int* __restrict__ rp_in, const int* __restrict__ rp_out,
        const float* __restrict__ part,
        int2* __restrict__ csr_in, int2* __restrict__ csr_out){
    __shared__ int lci[N_], lco[N_];
    int xcd  = blockIdx.x & 7;
    int r2   = blockIdx.x >> 3;
    int g    = xcd*4 + (r2 & 3);
    int b    = r2 >> 2;
    int tid  = threadIdx.x;
    int isf32 = flag[0];
    for (int i=tid;i<N_;i+=1024){ lci[i]=0; lco[i]=0; }
    __syncthreads();
    const int* eib = ei + g*2*E_;
    const int* cumI = (const int*)part + (size_t)(2*G_ + g)*NBLK_*N_ + (size_t)b*N_;
    const int* cumO = (const int*)part + (size_t)(3*G_ + g)*NBLK_*N_ + (size_t)b*N_;
    const int* rpi = rp_in  + g*(N_+1);
    const int* rpo = rp_out + g*(N_+1);
    int2* ci = csr_in  + (long)g*E_;
    int2* co = csr_out + (long)g*E_;
    int e0 = b*EPB_;
    for (int e=e0+tid; e<e0+EPB_; e+=1024){
        int s = eib[e], d = eib[E_+e];
        float dout = deg_o[g*N_+s], din = deg_i[g*N_+d];
        float io = dout > 0.f ? rsqrtf(fmaxf(dout, 1e-12f)) : 0.f;
        float ii = din  > 0.f ? rsqrtf(fmaxf(din , 1e-12f)) : 0.f;
        float nrm = loadf(ew, (long)g*E_ + e, isf32) * io * ii;
        int li = atomicAdd(&lci[d], 1);
        ci[rpi[d] + cumI[d] + li] = make_int2(s, __float_as_int(nrm));
        int lo = atomicAdd(&lco[s], 1);
        co[rpo[s] + cumO[s] + lo] = make_int2(d, __float_as_int(nrm));
    }
}

// ---------------- FUSED layer 0: gather(Xb) -> LDS A-tile -> MFMA -> Hb ----------------
// R12 version (row stride 144; passed at 515.9us).
__global__ __launch_bounds__(256) void g0fused(
        const int* __restrict__ rp_in, const int* __restrict__ rp_out,
        const int2* __restrict__ csr_in, const int2* __restrict__ csr_out,
        const unsigned short* __restrict__ Xb, const unsigned short* __restrict__ wc0,
        const float* __restrict__ wcv, __hip_bfloat16* __restrict__ Hb){
    __shared__ unsigned short As[64*144];
    int xcd  = blockIdx.x & 7;
    int tile = blockIdx.x >> 3;            // 0..249
    int m0   = (xcd*250 + tile)*64;        // row base in [0, GN)
    int tid  = threadIdx.x;

    int gid = tid >> 3, li = tid & 7;      // 32 groups x 8 lanes
    #pragma unroll
    for (int t=0; t<4; t++){
        int task = t*32 + gid;             // 0..127
        int dir  = task >> 6, r = task & 63;
        int grow = m0 + r;
        int g = grow / N_;  int n = grow - g*N_;
        const int*  rp  = (dir ? rp_out : rp_in) + g*(N_+1);
        const int2* csr = (dir ? csr_out : csr_in) + (long)g*E_;
        int pb = rp[n], pe = rp[n+1];
        int plast = max(pe - 1, 0);
        const unsigned short* base = Xb + (size_t)g*N_*64;
        float acc[8];
        #pragma unroll
        for (int j=0;j<8;j++) acc[j] = 0.f;
        for (int p=pb; p<pe; p+=4){
            float w4[4]; ushort8 v4[4];
            #pragma unroll
            for (int i=0;i<4;i++){
                int pi = p+i;
                int2 ent = csr[min(pi, plast)];
                w4[i] = (pi < pe) ? __int_as_float(ent.y) : 0.f;
                v4[i] = *(const ushort8*)(base + ent.x*64 + li*8);
            }
            #pragma unroll
            for (int i=0;i<4;i++)
                #pragma unroll
                for (int j=0;j<8;j++)
                    acc[j] += w4[i]*bfu2f(v4[i][j]);
        }
        ushort8 o;
        #pragma unroll
        for (int j=0;j<8;j++) o[j] = f2bfu(acc[j]);
        *(ushort8*)(&As[r*144 + dir*64 + li*8]) = o;
    }
    __syncthreads();

    int wave = tid >> 6, lane = tid & 63;
    int quad = lane >> 4, l16 = lane & 15;
    int colb = wave*16 + l16;              // 0..63
    bf16x8 bq[2][4];
    f32x4 acc[2][4];
    #pragma unroll
    for (int s=0;s<2;s++){
        #pragma unroll
        for (int ks=0;ks<4;ks++)
            bq[s][ks] = *(const bf16x8*)(wc0 + (size_t)(colb + s*64)*128 + ks*32 + quad*8);
        #pragma unroll
        for (int t=0;t<4;t++) acc[s][t] = (f32x4){0.f,0.f,0.f,0.f};
    }
    #pragma unroll
    for (int ks=0;ks<4;ks++){
        #pragma unroll
        for (int t=0;t<4;t++){
            bf16x8 a = *(const bf16x8*)(&As[(t*16 + l16)*144 + ks*32 + quad*8]);
            acc[0][t] = __builtin_amdgcn_mfma_f32_16x16x32_bf16(a, bq[0][ks], acc[0][t], 0, 0, 0);
            acc[1][t] = __builtin_amdgcn_mfma_f32_16x16x32_bf16(a, bq[1][ks], acc[1][t], 0, 0, 0);
        }
    }
    #pragma unroll
    for (int s=0;s<2;s++){
        int col = colb + s*64;
        float bias = 0.5f*(wcv[OFF_B0S+col] + wcv[OFF_B0D+col]);
        #pragma unroll
        for (int t=0;t<4;t++)
            #pragma unroll
            for (int r=0;r<4;r++)
                Hb[(size_t)(m0 + t*16 + quad*4 + r)*128 + col] = __float2bfloat16(acc[s][t][r] + bias);
    }
}

// ---------------- FUSED layer 1 + LSTM (32-row tile): gather(Hb) -> MFMA gates (LDS) ----------------
// -> 4-row x 8-step LSTM -> projection -> d_out. R14: R13's fusion with tile halved so
// LDS = As 17.4KB + gsh 33.3KB + hsh 1.25KB = 52KB -> 2-3 blocks/CU (R13: 105KB, 1/CU).
// LSTM rows 4..15 of the 16x16 MFMA are dead lanes: gates forced 0, writes guarded,
// A-rows >=4 read a shared zero row (hsh row 4).
__global__ __launch_bounds__(512) void gglstm(
        const int* __restrict__ rp_in, const int* __restrict__ rp_out,
        const int2* __restrict__ csr_in, const int2* __restrict__ csr_out,
        const unsigned short* __restrict__ hb,
        const unsigned short* __restrict__ wpc, const float* __restrict__ biasc,
        const unsigned short* __restrict__ whb, const float* __restrict__ wcv,
        const int* __restrict__ flag, void* __restrict__ out){
    __shared__ unsigned short As[32*272];    // gather/GEMM A-tile (17408 B)
    __shared__ unsigned short gsh[32*520];   // gates [graph-row r8][col] (33280 B)
    __shared__ unsigned short hsh[5*128];    // h rows 0..3 + zero row 4 (1280 B)
    int xcd  = blockIdx.x & 7;
    int tile = blockIdx.x >> 3;              // 0..499
    int m0   = (xcd*500 + tile)*32;          // graph-row base in [0, GN)
    int tid  = threadIdx.x;
    int isf32 = flag[0];

    for (int t=tid; t<5*128; t+=512) hsh[t] = 0;

    // ---- gather phase: 64 tasks (32 rows x 2 dirs), 32 groups x 16 lanes ----
    int gid = tid >> 4, li = tid & 15;
    #pragma unroll
    for (int t=0; t<2; t++){
        int task = t*32 + gid;               // 0..63
        int dir  = task >> 5, r = task & 31;
        int grow = m0 + r;
        int g = grow / N_;  int n = grow - g*N_;
        const int*  rp  = (dir ? rp_out : rp_in) + g*(N_+1);
        const int2* csr = (dir ? csr_out : csr_in) + (long)g*E_;
        int pb = rp[n], pe = rp[n+1];
        int plast = max(pe - 1, 0);
        const unsigned short* base = hb + (size_t)g*N_*128;
        float acc[8];
        #pragma unroll
        for (int j=0;j<8;j++) acc[j] = 0.f;
        for (int p=pb; p<pe; p+=4){
            float w4[4]; ushort8 v4[4];
            #pragma unroll
            for (int i=0;i<4;i++){
                int pi = p+i;
                int2 ent = csr[min(pi, plast)];
                w4[i] = (pi < pe) ? __int_as_float(ent.y) : 0.f;
                v4[i] = *(const ushort8*)(base + ent.x*128 + li*8);
            }
            #pragma unroll
            for (int i=0;i<4;i++)
                #pragma unroll
                for (int j=0;j<8;j++)
                    acc[j] += w4[i]*bfu2f(v4[i][j]);
        }
        ushort8 o;
        #pragma unroll
        for (int j=0;j<8;j++) o[j] = f2bfu(acc[j]);
        *(ushort8*)(&As[r*272 + dir*128 + li*8]) = o;
    }
    __syncthreads();

    // ---- GEMM phase: 32 rows x 512 cols, K=256, 4 col-passes; epilogue -> gsh ----
    int w = tid >> 6, lane = tid & 63;
    int quad = lane >> 4, l16 = lane & 15;
    for (int cs=0; cs<4; cs++){
        int col = cs*128 + w*16 + l16;
        bf16x8 bq[8];
        #pragma unroll
        for (int ks=0;ks<8;ks++)
            bq[ks] = *(const bf16x8*)(wpc + (size_t)col*256 + ks*32 + quad*8);
        f32x4 acc[2];
        #pragma unroll
        for (int t=0;t<2;t++) acc[t] = (f32x4){0.f,0.f,0.f,0.f};
        #pragma unroll
        for (int ks=0;ks<8;ks++)
            #pragma unroll
            for (int t=0;t<2;t++){
                bf16x8 a = *(const bf16x8*)(&As[(t*16 + l16)*272 + ks*32 + quad*8]);
                acc[t] = __builtin_amdgcn_mfma_f32_16x16x32_bf16(a, bq[ks], acc[t], 0, 0, 0);
            }
        float bc = biasc[col];
        #pragma unroll
        for (int t=0;t<2;t++)
            #pragma unroll
            for (int r=0;r<4;r++){
                int r8 = t*16 + quad*4 + r;          // graph-row within tile (0..31)
                gsh[r8*520 + col] = f2bfu(acc[t][r] + bc);
            }
    }
    __syncthreads();

    // ---- LSTM phase: 4 rows, 8 steps (R13 structure, rows<4 valid) ----
    int l15 = lane & 15;
    bf16x8 bfrag[4][4];
    #pragma unroll
    for (int g=0; g<4; g++)
        #pragma unroll
        for (int kt=0; kt<4; kt++)
            bfrag[g][kt] = *(const bf16x8*)(whb + (size_t)(g*128 + w*16 + l15)*128 + kt*32 + quad*8);

    int hrow_a = (l15 < 4) ? l15 : 4;        // A-rows >=4 read the shared zero row
    f32x4 c = (f32x4){0.f,0.f,0.f,0.f};
    #pragma unroll
    for (int step=0; step<8; step++){
        f32x4 acc[4];
        #pragma unroll
        for (int g=0; g<4; g++)
            #pragma unroll
            for (int r=0; r<4; r++){
                int row = quad*4 + r;                // LSTM row 0..15; valid 0..3
                acc[g][r] = (row < 4)
                    ? bfu2f(gsh[(8*row + step)*520 + g*128 + w*16 + l15]) : 0.f;
            }
        #pragma unroll
        for (int kt=0; kt<4; kt++){
            bf16x8 a = *(const bf16x8*)(&hsh[hrow_a*128 + (((kt*4+quad) ^ l15)<<3)]);
            #pragma unroll
            for (int g=0; g<4; g++)
                acc[g] = __builtin_amdgcn_mfma_f32_16x16x32_bf16(a, bfrag[g][kt], acc[g], 0, 0, 0);
        }
        float hnew[4];
        #pragma unroll
        for (int r=0; r<4; r++){
            float gi = sigmf(acc[0][r]), gf = sigmf(acc[1][r]);
            float gg = tanhfast(acc[2][r]), go = sigmf(acc[3][r]);
            float cc = gf*c[r] + gi*gg;
            c[r] = cc;
            hnew[r] = go*tanhfast(cc);
        }
        __syncthreads();
        #pragma unroll
        for (int r=0; r<4; r++){
            int row = quad*4 + r;
            if (row < 4){
                int idx = w*16 + l15;                // 0..127
                hsh[row*128 + (((idx>>3) ^ row)<<3) + (idx&7)] = f2bfu(hnew[r]);
            }
        }
        __syncthreads();
    }

    // ---- projection: 4 rows x 64 cols, threads 0..255 ----
    if (tid < 256){
        int r = tid >> 6;        // 0..3
        int q = tid & 63;        // 0..63
        float p = wcv[OFF_BP + q];
        for (int k4=0;k4<32;k4++){
            float4 hv = cvtbf4(*(const ushort4*)(&hsh[r*128 + (((k4>>1) ^ r)<<3) + (k4&1)*4]));
            float4 w0 = *(const float4*)(wcv + OFF_WP + q*128 + k4*4);
            p += w0.x*hv.x + w0.y*hv.y + w0.z*hv.z + w0.w*hv.w;
        }
        long o = (long)((m0>>3) + r)*64 + q;
        if (isf32) ((float*)out)[o] = p;
        else       ((__hip_bfloat16*)out)[o] = __float2bfloat16(p);
    }
}

extern "C" void kernel_launch(void* const* d_in, const int* in_sizes, int n_in,
                              void* d_out, int out_size, void* d_ws, size_t ws_size,
                              hipStream_t stream){
    const void* x_seq      = d_in[0];
    const int*  edge_index = (const int*)d_in[1];
    const void* edge_weight= d_in[2];

    float* ws    = (float*)d_ws;
    int*   flag  = (int*)(ws + WS_FLAG);
    float* wcv   = ws + WS_WCV;
    unsigned short* whb = (unsigned short*)(ws + WS_WPH);
    unsigned short* wpc = (unsigned short*)(ws + WS_WPC);
    unsigned short* wc0 = (unsigned short*)(ws + WS_WC0);
    float* biasc = ws + WS_BIASC;
    float* deg_o = ws + WS_DEGO;
    float* deg_i = ws + WS_DEGI;
    int*   cnt_i = (int*)(ws + WS_CNTI);
    int*   cnt_o = (int*)(ws + WS_CNTO);
    int*   rp_i  = (int*)(ws + WS_RPI);
    int*   rp_o  = (int*)(ws + WS_RPO);
    float* partb = ws + WS_PART;
    int2*  csr_i = (int2*)(ws + WS_CSRI);
    int2*  csr_o = (int2*)(ws + WS_CSRO);
    unsigned short* Xb = (unsigned short*)(ws + WS_X2);
    __hip_bfloat16* Hb = (__hip_bfloat16*)(ws + WS_HB);

    sniff_kernel<<<1, 256, 0, stream>>>((const unsigned int*)edge_weight, flag);
    WDesc wd;
    wd.seg[0]  = { d_in[3],  OFF_W0S, 8192  };
    wd.seg[1]  = { d_in[4],  OFF_B0S, 128   };
    wd.seg[2]  = { d_in[5],  OFF_W0D, 8192  };
    wd.seg[3]  = { d_in[6],  OFF_B0D, 128   };
    wd.seg[4]  = { d_in[7],  OFF_W1S, 16384 };
    wd.seg[5]  = { d_in[8],  OFF_B1S, 128   };
    wd.seg[6]  = { d_in[9],  OFF_W1D, 16384 };
    wd.seg[7]  = { d_in[10], OFF_B1D, 128   };
    wd.seg[8]  = { d_in[11], OFF_WIH, 65536 };
    wd.seg[9]  = { d_in[12], OFF_WHH, 65536 };
    wd.seg[10] = { d_in[13], OFF_BIH, 512   };
    wd.seg[11] = { d_in[14], OFF_BHH, 512   };
    wd.seg[12] = { d_in[15], OFF_WP,  8192  };
    wd.seg[13] = { d_in[16], OFF_BP,  64    };
    convert_weights<<<(WCV_TOTAL+255)/256, 256, 0, stream>>>(wd, wcv, flag);
    repack_whh<<<256, 256, 0, stream>>>(wcv, whb);
    repack_wc0<<<64, 256, 0, stream>>>(wcv, wc0);
    compose_wc<<<512, 256, 0, stream>>>(wcv, wpc);
    compose_bias<<<2, 256, 0, stream>>>(wcv, biasc);
    xcvt_kernel<<<(GN_*64+255)/256, 256, 0, stream>>>(x_seq, flag, Xb);

    hist_kernel<<<G_*NBLK_, 1024, 0, stream>>>(edge_index, edge_weight, flag, partb);
    reduce_hist<<<G_*16, 256, 0, stream>>>(partb, deg_o, deg_i, cnt_i, cnt_o);
    scan_kernel<<<64, 256, 0, stream>>>(cnt_i, cnt_o, rp_i, rp_o);
    fill_kernel<<<G_*NBLK_, 1024, 0, stream>>>(edge_index, edge_weight, flag,
                                               deg_o, deg_i, rp_i, rp_o, partb, csr_i, csr_o);

    // layer 0 fused: gather(Xb) + GEMM -> Hb
    g0fused<<<GN_/64, 256, 0, stream>>>(rp_i, rp_o, csr_i, csr_o, Xb, wc0, wcv, Hb);

    // layer 1 + LSTM fully fused (32-row tile): gather(Hb) + gates GEMM (LDS) + LSTM + proj -> out
    gglstm<<<GN_/32, 512, 0, stream>>>(rp_i, rp_o, csr_i, csr_o,
                                       (const unsigned short*)Hb, wpc, biasc,
                                       whb, wcv, flag, d_out);
}

// Round 15
// 481.085 us; speedup vs baseline: 1.2625x; 1.2625x over previous
//
#include <hip/hip_runtime.h>
#include <hip/hip_bf16.h>

// Problem constants (B,S,N,F,H,E) = (4,8,4000,64,128,32000)
#define B_  4
#define S_  8
#define N_  4000
#define F_  64
#define H_  128
#define E_  32000
#define G_  (B_*S_)        // 32 graphs
#define GN_ (G_*N_)        // 128000 node rows
#define M_  (B_*N_)        // 16000 LSTM rows
#define GE_ (G_*E_)        // 1,024,000 edges total
#define HALF_GN 64000
#define HALF_M  8000
#define NBLK_   8          // hist/fill blocks per graph
#define EPB_    (E_/NBLK_) // 4000 edges per block

// f32 weight scratch offsets (floats)
#define OFF_W0S 0
#define OFF_B0S 8192
#define OFF_W0D 8320
#define OFF_B0D 16512
#define OFF_W1S 16640
#define OFF_B1S 33024
#define OFF_W1D 33152
#define OFF_B1D 49536
#define OFF_WIH 49664
#define OFF_WHH 115200
#define OFF_BIH 180736
#define OFF_BHH 181248
#define OFF_WP  181760
#define OFF_BP  189952
#define WCV_TOTAL 190016

// workspace layout (float offsets)
#define WS_FLAG   0
#define WS_WCV    16
#define WS_WPH    190032      // Whh bf16 [512][128]: 65536 ushorts
#define WS_WPC    222800      // composed Wc bf16 [512][256]: 131072 ushorts
#define WS_BIASC  288336      // 512 f32
#define WS_DEGO   288848      // deg_o, deg_i, cnt_i, cnt_o contiguous: 4 x 128000 words
#define WS_DEGI   416848
#define WS_CNTI   544848
#define WS_CNTO   672848
#define WS_RPI    800848      // 32*4001
#define WS_RPO    928880
#define WS_CSRI   1312912     // int2 x GE
#define WS_CSRO   3360912
#define WS_X2     5408912     // Xb [GN][64] bf16; after g0fused: GT2 gates3 h1 [8000][512][8]
#define WS_PART   9608912     // hist partials 4 x [32][8][4000] words = 4,096,000 floats
#define WS_HB     21792912    // [GN][128] bf16
#define WS_GT     29984912    // gates3 h0 [8000][512][8] bf16
#define WS_WC0    46368912    // Wc0 bf16 [128][128]: 16384 ushorts = 8192 floats
// end: 46,377,104 floats = 185.5 MiB (proven budget >= 193 MiB)

typedef __attribute__((ext_vector_type(8))) short bf16x8;
typedef __attribute__((ext_vector_type(4))) float f32x4;
typedef __attribute__((ext_vector_type(8))) unsigned short ushort8;

__device__ inline float bfu2f(unsigned short u){ union{unsigned int i; float f;} v; v.i=((unsigned int)u)<<16; return v.f; }
__device__ inline unsigned short f2bfu(float f){ __hip_bfloat16 b = __float2bfloat16(f); return *(unsigned short*)&b; }
__device__ inline float rcpf(float x){ return __builtin_amdgcn_rcpf(x); }
__device__ inline float sigmf(float x){ return rcpf(1.0f + __expf(-x)); }
__device__ inline float tanhfast(float x){ return 1.0f - 2.0f*rcpf(1.0f + __expf(2.0f*x)); }
__device__ inline float loadf(const void* p, long i, int isf32){
    return isf32 ? ((const float*)p)[i]
                 : __bfloat162float(((const __hip_bfloat16*)p)[i]);
}
__device__ inline float4 cvtbf4(ushort4 u){
    float4 f;
    f.x = __uint_as_float(((unsigned)u.x)<<16);
    f.y = __uint_as_float(((unsigned)u.y)<<16);
    f.z = __uint_as_float(((unsigned)u.z)<<16);
    f.w = __uint_as_float(((unsigned)u.w)<<16);
    return f;
}

// ---------------- dtype sniff (inputs f32 vs bf16) ----------------
__global__ void sniff_kernel(const unsigned int* __restrict__ ew, int* __restrict__ flag){
    __shared__ int s;
    if (threadIdx.x == 0) s = 0;
    __syncthreads();
    unsigned int lo = ew[threadIdx.x] & 0xFFFFu;
    if (lo > 0x3F80u) atomicOr(&s, 1);
    __syncthreads();
    if (threadIdx.x == 0) flag[0] = s;   // 1 => inputs are f32
}

// ---------------- weight conversion to f32 scratch ----------------
struct WSeg { const void* src; int base; int n; };
struct WDesc { WSeg seg[14]; };
__global__ void convert_weights(WDesc d, float* __restrict__ dst, const int* __restrict__ flag){
    int isf32 = flag[0];
    int idx = blockIdx.x*256 + threadIdx.x;
    #pragma unroll
    for (int s=0;s<14;s++){
        int off = idx - d.seg[s].base;
        if (off >= 0 && off < d.seg[s].n){
            dst[idx] = loadf(d.seg[s].src, off, isf32);
            return;
        }
    }
}

// ---------------- Whh bf16 copy ----------------
__global__ void repack_whh(const float* __restrict__ wcv, unsigned short* __restrict__ whb){
    int idx = blockIdx.x*256 + threadIdx.x;   // < 65536
    whb[idx] = f2bfu(wcv[OFF_WHH + idx]);
}

// ---------------- layer-0 composed weights: Wc0[n][k] bf16 [128][128] ----------------
__global__ void repack_wc0(const float* __restrict__ wcv, unsigned short* __restrict__ wc0){
    int idx = blockIdx.x*256 + threadIdx.x;   // < 16384
    int k = idx & 127, n = idx >> 7;
    float v = (k < 64) ? 0.5f*wcv[OFF_W0S + n*64 + k] : 0.5f*wcv[OFF_W0D + n*64 + (k-64)];
    wc0[idx] = f2bfu(v);
}

// ---------------- x_seq -> bf16 Xb [GN][64] ----------------
__global__ void xcvt_kernel(const void* __restrict__ x, const int* __restrict__ flag,
                            unsigned short* __restrict__ Xb){
    long idx = (long)blockIdx.x*256 + threadIdx.x;
    if (idx >= (long)GN_*64) return;
    Xb[idx] = f2bfu(loadf(x, idx, flag[0]));
}

// ---------------- composed weights: Wc[n][k] bf16 [512][256] ----------------
__global__ __launch_bounds__(256) void compose_wc(const float* __restrict__ wcv,
                                                  unsigned short* __restrict__ wpc){
    int n = blockIdx.x;        // 512 blocks
    int k = threadIdx.x;       // 256
    const float* wih = wcv + OFF_WIH + n*128;
    const float* w1  = (k < 128) ? (wcv + OFF_W1S + k) : (wcv + OFF_W1D + (k-128));
    float s = 0.f;
    for (int h=0; h<128; h++) s += wih[h] * w1[h*128];
    wpc[n*256 + k] = f2bfu(0.5f * s);
}

// biasc[n] = bih[n]+bhh[n] + sum_h Wih[n][h]*0.5*(b1s[h]+b1d[h])
__global__ void compose_bias(const float* __restrict__ wcv, float* __restrict__ biasc){
    int n = blockIdx.x*256 + threadIdx.x;
    if (n >= 512) return;
    float s = wcv[OFF_BIH+n] + wcv[OFF_BHH+n];
    const float* wih = wcv + OFF_WIH + n*128;
    for (int h=0; h<128; h++) s += wih[h] * 0.5f*(wcv[OFF_B1S+h] + wcv[OFF_B1D+h]);
    biasc[n] = s;
}

// ---------------- histogram: per-(graph, edge-block) LDS partials ----------------
__global__ __launch_bounds__(1024) void hist_kernel(
        const int* __restrict__ ei, const void* __restrict__ ew, const int* __restrict__ flag,
        float* __restrict__ part){
    __shared__ float wdo[N_], wdi[N_];
    __shared__ int   co[N_],  ci[N_];
    int xcd  = blockIdx.x & 7;
    int r2   = blockIdx.x >> 3;
    int g    = xcd*4 + (r2 & 3);
    int b    = r2 >> 2;                     // 0..7
    int tid  = threadIdx.x;
    int isf32 = flag[0];
    for (int i=tid;i<N_;i+=1024){ wdo[i]=0.f; wdi[i]=0.f; co[i]=0; ci[i]=0; }
    __syncthreads();
    const int* eib = ei + g*2*E_;
    int e0 = b*EPB_;
    for (int e=e0+tid; e<e0+EPB_; e+=1024){
        int s = eib[e], d = eib[E_+e];
        float w = loadf(ew, (long)g*E_+e, isf32);
        atomicAdd(&wdo[s], w); atomicAdd(&wdi[d], w);
        atomicAdd(&co[s], 1);  atomicAdd(&ci[d], 1);
    }
    __syncthreads();
    float* Pdo = part + (size_t)(0*G_ + g)*NBLK_*N_ + (size_t)b*N_;
    float* Pdi = part + (size_t)(1*G_ + g)*NBLK_*N_ + (size_t)b*N_;
    int*   Pci = (int*)part + (size_t)(2*G_ + g)*NBLK_*N_ + (size_t)b*N_;
    int*   Pco = (int*)part + (size_t)(3*G_ + g)*NBLK_*N_ + (size_t)b*N_;
    for (int i=tid;i<N_;i+=1024){
        Pdo[i] = wdo[i]; Pdi[i] = wdi[i];
        Pci[i] = ci[i];  Pco[i] = co[i];
    }
}

// ---------------- reduce partials -> deg/cnt; counts -> per-block exclusive prefix ----------------
__global__ __launch_bounds__(256) void reduce_hist(
        float* __restrict__ part,
        float* __restrict__ deg_o, float* __restrict__ deg_i,
        int* __restrict__ cnt_in, int* __restrict__ cnt_out){
    int g = blockIdx.x >> 4;
    int n = (blockIdx.x & 15)*256 + threadIdx.x;
    if (n >= N_) return;
    float* Pdo = part + (size_t)(0*G_ + g)*NBLK_*N_;
    float* Pdi = part + (size_t)(1*G_ + g)*NBLK_*N_;
    int*   Pci = (int*)part + (size_t)(2*G_ + g)*NBLK_*N_;
    int*   Pco = (int*)part + (size_t)(3*G_ + g)*NBLK_*N_;
    float sdo = 0.f, sdi = 0.f;
    int sci = 0, sco = 0;
    #pragma unroll
    for (int b=0;b<NBLK_;b++){
        size_t idx = (size_t)b*N_ + n;
        sdo += Pdo[idx]; sdi += Pdi[idx];
        int vi = Pci[idx], vo = Pco[idx];
        Pci[idx] = sci;  Pco[idx] = sco;   // exclusive prefix for fill
        sci += vi; sco += vo;
    }
    deg_o[g*N_+n] = sdo; deg_i[g*N_+n] = sdi;
    cnt_in[g*N_+n] = sci; cnt_out[g*N_+n] = sco;
}

// ---------------- exclusive scan -> row_ptr ----------------
__global__ __launch_bounds__(256) void scan_kernel(
        const int* __restrict__ cnt_in, const int* __restrict__ cnt_out,
        int* __restrict__ rp_in, int* __restrict__ rp_out){
    __shared__ int part[256], pref[256];
    int g = blockIdx.x & 31, dir = blockIdx.x >> 5;
    const int* cnt = (dir ? cnt_out : cnt_in) + g*N_;
    int* rp  = (dir ? rp_out  : rp_in)  + g*(N_+1);
    int tid = threadIdx.x, base = tid*16;
    int sum = 0;
    for (int i=0;i<16;i++){ int p = base+i; if (p < N_) sum += cnt[p]; }
    part[tid] = sum;
    __syncthreads();
    if (tid == 0){ int run = 0; for (int j=0;j<256;j++){ pref[j] = run; run += part[j]; } }
    __syncthreads();
    int run = pref[tid];
    for (int i=0;i<16;i++){
        int p = base+i;
        if (p < N_){ rp[p] = run; run += cnt[p]; }
    }
    if (tid == 255) rp[N_] = run;
}

// ---------------- fill CSR (no global atomics) ----------------
__global__ __launch_bounds__(1024) void fill_kernel(
        const int* __restrict__ ei, const void* __restrict__ ew,
        const int* __restrict__ flag,
        const float* __restrict__ deg_o, const float* __restrict__ deg_i,
        const int* __restrict__ rp_in, const int* __restrict__ rp_out,
        const float* __restrict__ part,
        int2* __restrict__ csr_in, int2* __restrict__ csr_out){
    __shared__ int lci[N_], lco[N_];
    int xcd  = blockIdx.x & 7;
    int r2   = blockIdx.x >> 3;
    int g    = xcd*4 + (r2 & 3);
    int b    = r2 >> 2;
    int tid  = threadIdx.x;
    int isf32 = flag[0];
    for (int i=tid;i<N_;i+=1024){ lci[i]=0; lco[i]=0; }
    __syncthreads();
    const int* eib = ei + g*2*E_;
    const int* cumI = (const int*)part + (size_t)(2*G_ + g)*NBLK_*N_ + (size_t)b*N_;
    const int* cumO = (const int*)part + (size_t)(3*G_ + g)*NBLK_*N_ + (size_t)b*N_;
    const int* rpi = rp_in  + g*(N_+1);
    const int* rpo = rp_out + g*(N_+1);
    int2* ci = csr_in  + (long)g*E_;
    int2* co = csr_out + (long)g*E_;
    int e0 = b*EPB_;
    for (int e=e0+tid; e<e0+EPB_; e+=1024){
        int s = eib[e], d = eib[E_+e];
        float dout = deg_o[g*N_+s], din = deg_i[g*N_+d];
        float io = dout > 0.f ? rsqrtf(fmaxf(dout, 1e-12f)) : 0.f;
        float ii = din  > 0.f ? rsqrtf(fmaxf(din , 1e-12f)) : 0.f;
        float nrm = loadf(ew, (long)g*E_ + e, isf32) * io * ii;
        int li = atomicAdd(&lci[d], 1);
        ci[rpi[d] + cumI[d] + li] = make_int2(s, __float_as_int(nrm));
        int lo = atomicAdd(&lco[s], 1);
        co[rpo[s] + cumO[s] + lo] = make_int2(d, __float_as_int(nrm));
    }
}

// ---------------- FUSED layer 0: gather(Xb) -> LDS A-tile -> MFMA -> Hb ----------------
// R12 version (row stride 144; passed at 515.9us).
__global__ __launch_bounds__(256) void g0fused(
        const int* __restrict__ rp_in, const int* __restrict__ rp_out,
        const int2* __restrict__ csr_in, const int2* __restrict__ csr_out,
        const unsigned short* __restrict__ Xb, const unsigned short* __restrict__ wc0,
        const float* __restrict__ wcv, __hip_bfloat16* __restrict__ Hb){
    __shared__ unsigned short As[64*144];
    int xcd  = blockIdx.x & 7;
    int tile = blockIdx.x >> 3;            // 0..249
    int m0   = (xcd*250 + tile)*64;        // row base in [0, GN)
    int tid  = threadIdx.x;

    int gid = tid >> 3, li = tid & 7;      // 32 groups x 8 lanes
    #pragma unroll
    for (int t=0; t<4; t++){
        int task = t*32 + gid;             // 0..127
        int dir  = task >> 6, r = task & 63;
        int grow = m0 + r;
        int g = grow / N_;  int n = grow - g*N_;
        const int*  rp  = (dir ? rp_out : rp_in) + g*(N_+1);
        const int2* csr = (dir ? csr_out : csr_in) + (long)g*E_;
        int pb = rp[n], pe = rp[n+1];
        int plast = max(pe - 1, 0);
        const unsigned short* base = Xb + (size_t)g*N_*64;
        float acc[8];
        #pragma unroll
        for (int j=0;j<8;j++) acc[j] = 0.f;
        for (int p=pb; p<pe; p+=4){
            float w4[4]; ushort8 v4[4];
            #pragma unroll
            for (int i=0;i<4;i++){
                int pi = p+i;
                int2 ent = csr[min(pi, plast)];
                w4[i] = (pi < pe) ? __int_as_float(ent.y) : 0.f;
                v4[i] = *(const ushort8*)(base + ent.x*64 + li*8);
            }
            #pragma unroll
            for (int i=0;i<4;i++)
                #pragma unroll
                for (int j=0;j<8;j++)
                    acc[j] += w4[i]*bfu2f(v4[i][j]);
        }
        ushort8 o;
        #pragma unroll
        for (int j=0;j<8;j++) o[j] = f2bfu(acc[j]);
        *(ushort8*)(&As[r*144 + dir*64 + li*8]) = o;
    }
    __syncthreads();

    int wave = tid >> 6, lane = tid & 63;
    int quad = lane >> 4, l16 = lane & 15;
    int colb = wave*16 + l16;              // 0..63
    bf16x8 bq[2][4];
    f32x4 acc[2][4];
    #pragma unroll
    for (int s=0;s<2;s++){
        #pragma unroll
        for (int ks=0;ks<4;ks++)
            bq[s][ks] = *(const bf16x8*)(wc0 + (size_t)(colb + s*64)*128 + ks*32 + quad*8);
        #pragma unroll
        for (int t=0;t<4;t++) acc[s][t] = (f32x4){0.f,0.f,0.f,0.f};
    }
    #pragma unroll
    for (int ks=0;ks<4;ks++){
        #pragma unroll
        for (int t=0;t<4;t++){
            bf16x8 a = *(const bf16x8*)(&As[(t*16 + l16)*144 + ks*32 + quad*8]);
            acc[0][t] = __builtin_amdgcn_mfma_f32_16x16x32_bf16(a, bq[0][ks], acc[0][t], 0, 0, 0);
            acc[1][t] = __builtin_amdgcn_mfma_f32_16x16x32_bf16(a, bq[1][ks], acc[1][t], 0, 0, 0);
        }
    }
    #pragma unroll
    for (int s=0;s<2;s++){
        int col = colb + s*64;
        float bias = 0.5f*(wcv[OFF_B0S+col] + wcv[OFF_B0D+col]);
        #pragma unroll
        for (int t=0;t<4;t++)
            #pragma unroll
            for (int r=0;r<4;r++)
                Hb[(size_t)(m0 + t*16 + quad*4 + r)*128 + col] = __float2bfloat16(acc[s][t][r] + bias);
    }
}

// ---------------- FUSED layer 1: gather(Hb) -> LDS A-tile -> MFMA -> gates3 ----------------
// R15: both halves in ONE 2000-block launch (h0 -> gatesA at WS_GT, h1 -> gatesB
// aliasing the dead Xb/X2 region). Per-half XCD swizzle preserved. Hot loops = R12.
__global__ __launch_bounds__(512) void ggfused(
        const int* __restrict__ rp_in, const int* __restrict__ rp_out,
        const int2* __restrict__ csr_in, const int2* __restrict__ csr_out,
        const unsigned short* __restrict__ hb,
        const unsigned short* __restrict__ wpc, const float* __restrict__ biasc,
        unsigned short* __restrict__ gatesA, unsigned short* __restrict__ gatesB){
    __shared__ unsigned short As[64*272];
    int xcd   = blockIdx.x & 7;
    int tA    = blockIdx.x >> 3;           // 0..249
    int half  = tA >= 125;
    int tile  = tA - 125*half;             // 0..124
    int m0    = (xcd*125 + tile)*64;       // row base within half
    int gn_base = half*HALF_GN;
    unsigned short* gates = half ? gatesB : gatesA;
    int tid  = threadIdx.x;

    // ---- gather phase ----
    int gid = tid >> 4, li = tid & 15;     // 32 groups x 16 lanes
    #pragma unroll
    for (int t=0; t<4; t++){
        int task = t*32 + gid;             // 0..127
        int dir  = task >> 6, r = task & 63;
        int grow = gn_base + m0 + r;
        int g = grow / N_;  int n = grow - g*N_;
        const int*  rp  = (dir ? rp_out : rp_in) + g*(N_+1);
        const int2* csr = (dir ? csr_out : csr_in) + (long)g*E_;
        int pb = rp[n], pe = rp[n+1];
        int plast = max(pe - 1, 0);
        const unsigned short* base = hb + (size_t)g*N_*128;
        float acc[8];
        #pragma unroll
        for (int j=0;j<8;j++) acc[j] = 0.f;
        for (int p=pb; p<pe; p+=4){
            float w4[4]; ushort8 v4[4];
            #pragma unroll
            for (int i=0;i<4;i++){
                int pi = p+i;
                int2 ent = csr[min(pi, plast)];
                w4[i] = (pi < pe) ? __int_as_float(ent.y) : 0.f;
                v4[i] = *(const ushort8*)(base + ent.x*128 + li*8);
            }
            #pragma unroll
            for (int i=0;i<4;i++)
                #pragma unroll
                for (int j=0;j<8;j++)
                    acc[j] += w4[i]*bfu2f(v4[i][j]);
        }
        ushort8 o;
        #pragma unroll
        for (int j=0;j<8;j++) o[j] = f2bfu(acc[j]);
        *(ushort8*)(&As[r*272 + dir*128 + li*8]) = o;
    }
    __syncthreads();

    // ---- GEMM phase: 64 rows x 512 cols, K=256, 4 col-passes ----
    int w = tid >> 6, lane = tid & 63;
    int quad = lane >> 4, l16 = lane & 15;
    for (int cs=0; cs<4; cs++){
        int col = cs*128 + w*16 + l16;
        bf16x8 bq[8];
        #pragma unroll
        for (int ks=0;ks<8;ks++)
            bq[ks] = *(const bf16x8*)(wpc + (size_t)col*256 + ks*32 + quad*8);
        f32x4 acc[4];
        #pragma unroll
        for (int t=0;t<4;t++) acc[t] = (f32x4){0.f,0.f,0.f,0.f};
        #pragma unroll
        for (int ks=0;ks<8;ks++)
            #pragma unroll
            for (int t=0;t<4;t++){
                bf16x8 a = *(const bf16x8*)(&As[(t*16 + l16)*272 + ks*32 + quad*8]);
                acc[t] = __builtin_amdgcn_mfma_f32_16x16x32_bf16(a, bq[ks], acc[t], 0, 0, 0);
            }
        float bc = biasc[col];
        #pragma unroll
        for (int t=0;t<4;t++)
            #pragma unroll
            for (int r=0;r<4;r++){
                int grow = m0 + t*16 + quad*4 + r;    // gl = m*8 + step (within half)
                gates[(size_t)(grow>>3)*4096 + (size_t)col*8 + (grow&7)] = f2bfu(acc[t][r] + bc);
            }
    }
}

// ---------------- MFMA recurrent LSTM (8 steps) + projection ----------------
// R15: both halves in ONE 1000-block launch; gates pointer chosen per block.
__global__ __launch_bounds__(512) void lstm7(
        const unsigned short* __restrict__ gatesA, const unsigned short* __restrict__ gatesB,
        const unsigned short* __restrict__ whb,
        const float* __restrict__ wcv, const int* __restrict__ flag,
        void* __restrict__ out){
    __shared__ unsigned short hsh[16*128];
    int tid  = threadIdx.x;
    int w    = tid >> 6;
    int lane = tid & 63;
    int quad = lane >> 4, l15 = lane & 15;
    int mb   = blockIdx.x;               // 0..999
    int half = mb >= 500;
    int mlb  = (mb - 500*half) * 16;     // row base within half
    int m0   = half*HALF_M + mlb;        // global row base (output)
    const unsigned short* gates3 = half ? gatesB : gatesA;
    int isf32 = flag[0];

    ushort8 pg[4][4];
    const unsigned short* gb = gates3 + (size_t)mlb*4096 + (size_t)(w*16 + l15)*8;
    #pragma unroll
    for (int g=0; g<4; g++)
        #pragma unroll
        for (int r=0; r<4; r++)
            pg[g][r] = *(const ushort8*)(gb + (size_t)(quad*4+r)*4096 + (size_t)g*1024);

    bf16x8 bfrag[4][4];
    #pragma unroll
    for (int g=0; g<4; g++)
        #pragma unroll
        for (int kt=0; kt<4; kt++)
            bfrag[g][kt] = *(const bf16x8*)(whb + (size_t)(g*128 + w*16 + l15)*128 + kt*32 + quad*8);

    for (int t=tid; t<16*128; t+=512) hsh[t] = 0;
    f32x4 c = (f32x4){0.f,0.f,0.f,0.f};
    __syncthreads();

    #pragma unroll
    for (int step=0; step<8; step++){
        f32x4 acc[4];
        #pragma unroll
        for (int g=0; g<4; g++)
            #pragma unroll
            for (int r=0; r<4; r++)
                acc[g][r] = bfu2f(pg[g][r][step]);
        #pragma unroll
        for (int kt=0; kt<4; kt++){
            bf16x8 a = *(const bf16x8*)(&hsh[l15*128 + (((kt*4+quad) ^ (l15&15))<<3)]);
            #pragma unroll
            for (int g=0; g<4; g++)
                acc[g] = __builtin_amdgcn_mfma_f32_16x16x32_bf16(a, bfrag[g][kt], acc[g], 0, 0, 0);
        }
        float hnew[4];
        #pragma unroll
        for (int r=0; r<4; r++){
            float gi = sigmf(acc[0][r]), gf = sigmf(acc[1][r]);
            float gg = tanhfast(acc[2][r]), go = sigmf(acc[3][r]);
            float cc = gf*c[r] + gi*gg;
            c[r] = cc;
            hnew[r] = go*tanhfast(cc);
        }
        __syncthreads();
        #pragma unroll
        for (int r=0; r<4; r++){
            int row = quad*4 + r;
            int idx = w*16 + l15;                 // 0..127
            hsh[row*128 + (((idx>>3) ^ (row&15))<<3) + (idx&7)] = f2bfu(hnew[r]);
        }
        __syncthreads();
    }
    int r  = tid >> 5;
    int q0 = (tid & 31) * 2;
    float p0 = wcv[OFF_BP + q0], p1 = wcv[OFF_BP + q0 + 1];
    for (int k4=0;k4<32;k4++){
        float4 hv = cvtbf4(*(const ushort4*)(&hsh[r*128 + (((k4>>1) ^ (r&15))<<3) + (k4&1)*4]));
        float4 w0 = *(const float4*)(wcv + OFF_WP + q0*128 + k4*4);
        float4 w1 = *(const float4*)(wcv + OFF_WP + (q0+1)*128 + k4*4);
        p0 += w0.x*hv.x + w0.y*hv.y + w0.z*hv.z + w0.w*hv.w;
        p1 += w1.x*hv.x + w1.y*hv.y + w1.z*hv.z + w1.w*hv.w;
    }
    long o = (long)(m0+r)*64 + q0;
    if (isf32){ ((float*)out)[o] = p0; ((float*)out)[o+1] = p1; }
    else { ((__hip_bfloat16*)out)[o] = __float2bfloat16(p0);
           ((__hip_bfloat16*)out)[o+1] = __float2bfloat16(p1); }
}

extern "C" void kernel_launch(void* const* d_in, const int* in_sizes, int n_in,
                              void* d_out, int out_size, void* d_ws, size_t ws_size,
                              hipStream_t stream){
    const void* x_seq      = d_in[0];
    const int*  edge_index = (const int*)d_in[1];
    const void* edge_weight= d_in[2];

    float* ws    = (float*)d_ws;
    int*   flag  = (int*)(ws + WS_FLAG);
    float* wcv   = ws + WS_WCV;
    unsigned short* whb = (unsigned short*)(ws + WS_WPH);
    unsigned short* wpc = (unsigned short*)(ws + WS_WPC);
    unsigned short* wc0 = (unsigned short*)(ws + WS_WC0);
    float* biasc = ws + WS_BIASC;
    float* deg_o = ws + WS_DEGO;
    float* deg_i = ws + WS_DEGI;
    int*   cnt_i = (int*)(ws + WS_CNTI);
    int*   cnt_o = (int*)(ws + WS_CNTO);
    int*   rp_i  = (int*)(ws + WS_RPI);
    int*   rp_o  = (int*)(ws + WS_RPO);
    float* partb = ws + WS_PART;
    int2*  csr_i = (int2*)(ws + WS_CSRI);
    int2*  csr_o = (int2*)(ws + WS_CSRO);
    unsigned short* Xb  = (unsigned short*)(ws + WS_X2);
    unsigned short* GT2 = (unsigned short*)(ws + WS_X2);   // aliases Xb (dead after g0fused)
    __hip_bfloat16* Hb = (__hip_bfloat16*)(ws + WS_HB);
    unsigned short* GT = (unsigned short*)(ws + WS_GT);

    sniff_kernel<<<1, 256, 0, stream>>>((const unsigned int*)edge_weight, flag);
    WDesc wd;
    wd.seg[0]  = { d_in[3],  OFF_W0S, 8192  };
    wd.seg[1]  = { d_in[4],  OFF_B0S, 128   };
    wd.seg[2]  = { d_in[5],  OFF_W0D, 8192  };
    wd.seg[3]  = { d_in[6],  OFF_B0D, 128   };
    wd.seg[4]  = { d_in[7],  OFF_W1S, 16384 };
    wd.seg[5]  = { d_in[8],  OFF_B1S, 128   };
    wd.seg[6]  = { d_in[9],  OFF_W1D, 16384 };
    wd.seg[7]  = { d_in[10], OFF_B1D, 128   };
    wd.seg[8]  = { d_in[11], OFF_WIH, 65536 };
    wd.seg[9]  = { d_in[12], OFF_WHH, 65536 };
    wd.seg[10] = { d_in[13], OFF_BIH, 512   };
    wd.seg[11] = { d_in[14], OFF_BHH, 512   };
    wd.seg[12] = { d_in[15], OFF_WP,  8192  };
    wd.seg[13] = { d_in[16], OFF_BP,  64    };
    convert_weights<<<(WCV_TOTAL+255)/256, 256, 0, stream>>>(wd, wcv, flag);
    repack_whh<<<256, 256, 0, stream>>>(wcv, whb);
    repack_wc0<<<64, 256, 0, stream>>>(wcv, wc0);
    compose_wc<<<512, 256, 0, stream>>>(wcv, wpc);
    compose_bias<<<2, 256, 0, stream>>>(wcv, biasc);
    xcvt_kernel<<<(GN_*64+255)/256, 256, 0, stream>>>(x_seq, flag, Xb);

    hist_kernel<<<G_*NBLK_, 1024, 0, stream>>>(edge_index, edge_weight, flag, partb);
    reduce_hist<<<G_*16, 256, 0, stream>>>(partb, deg_o, deg_i, cnt_i, cnt_o);
    scan_kernel<<<64, 256, 0, stream>>>(cnt_i, cnt_o, rp_i, rp_o);
    fill_kernel<<<G_*NBLK_, 1024, 0, stream>>>(edge_index, edge_weight, flag,
                                               deg_o, deg_i, rp_i, rp_o, partb, csr_i, csr_o);

    // layer 0 fused: gather(Xb) + GEMM -> Hb   (Xb dead afterwards; region reused as GT2)
    g0fused<<<GN_/64, 256, 0, stream>>>(rp_i, rp_o, csr_i, csr_o, Xb, wc0, wcv, Hb);

    // layer 1 fused, both halves in one launch: gather(Hb) + gates GEMM -> GT / GT2
    ggfused<<<GN_/64, 512, 0, stream>>>(rp_i, rp_o, csr_i, csr_o,
                                        (const unsigned short*)Hb, wpc, biasc, GT, GT2);

    // LSTM + projection, both halves in one launch
    lstm7<<<M_/16, 512, 0, stream>>>(GT, GT2, whb, wcv, flag, d_out);
}

// Round 16
// 474.571 us; speedup vs baseline: 1.2799x; 1.0137x over previous
//
#include <hip/hip_runtime.h>
#include <hip/hip_bf16.h>

// Problem constants (B,S,N,F,H,E) = (4,8,4000,64,128,32000)
#define B_  4
#define S_  8
#define N_  4000
#define F_  64
#define H_  128
#define E_  32000
#define G_  (B_*S_)        // 32 graphs
#define GN_ (G_*N_)        // 128000 node rows
#define M_  (B_*N_)        // 16000 LSTM rows
#define GE_ (G_*E_)        // 1,024,000 edges total
#define HALF_GN 64000
#define HALF_M  8000
#define NBLK_   8          // hist/fill blocks per graph
#define EPB_    (E_/NBLK_) // 4000 edges per block
#define XCVT_BLK 32000     // (GN*64)/256

// f32 weight scratch offsets (floats)
#define OFF_W0S 0
#define OFF_B0S 8192
#define OFF_W0D 8320
#define OFF_B0D 16512
#define OFF_W1S 16640
#define OFF_B1S 33024
#define OFF_W1D 33152
#define OFF_B1D 49536
#define OFF_WIH 49664
#define OFF_WHH 115200
#define OFF_BIH 180736
#define OFF_BHH 181248
#define OFF_WP  181760
#define OFF_BP  189952
#define WCV_TOTAL 190016

// workspace layout (float offsets)
#define WS_FLAG   0
#define WS_WCV    16
#define WS_WPH    190032      // Whh bf16 [512][128]: 65536 ushorts
#define WS_WPC    222800      // composed Wc bf16 [512][256]: 131072 ushorts
#define WS_BIASC  288336      // 512 f32
#define WS_DEGO   288848      // deg_o, deg_i, cnt_i, cnt_o contiguous: 4 x 128000 words
#define WS_DEGI   416848
#define WS_CNTI   544848
#define WS_CNTO   672848
#define WS_RPI    800848      // 32*4001
#define WS_RPO    928880
#define WS_CSRI   1312912     // int2 x GE
#define WS_CSRO   3360912
#define WS_X2     5408912     // Xb [GN][64] bf16; after g0fused: GT2 gates3 h1 [8000][512][8]
#define WS_PART   9608912     // hist partials 4 x [32][8][4000] words = 4,096,000 floats
#define WS_HB     21792912    // [GN][128] bf16
#define WS_GT     29984912    // gates3 h0 [8000][512][8] bf16
#define WS_WC0    46368912    // Wc0 bf16 [128][128]: 16384 ushorts = 8192 floats
// end: 46,377,104 floats = 185.5 MiB (proven budget >= 193 MiB)

typedef __attribute__((ext_vector_type(8))) short bf16x8;
typedef __attribute__((ext_vector_type(4))) float f32x4;
typedef __attribute__((ext_vector_type(8))) unsigned short ushort8;

__device__ inline float bfu2f(unsigned short u){ union{unsigned int i; float f;} v; v.i=((unsigned int)u)<<16; return v.f; }
__device__ inline unsigned short f2bfu(float f){ __hip_bfloat16 b = __float2bfloat16(f); return *(unsigned short*)&b; }
__device__ inline float rcpf(float x){ return __builtin_amdgcn_rcpf(x); }
__device__ inline float sigmf(float x){ return rcpf(1.0f + __expf(-x)); }
__device__ inline float tanhfast(float x){ return 1.0f - 2.0f*rcpf(1.0f + __expf(2.0f*x)); }
__device__ inline float loadf(const void* p, long i, int isf32){
    return isf32 ? ((const float*)p)[i]
                 : __bfloat162float(((const __hip_bfloat16*)p)[i]);
}
__device__ inline float4 cvtbf4(ushort4 u){
    float4 f;
    f.x = __uint_as_float(((unsigned)u.x)<<16);
    f.y = __uint_as_float(((unsigned)u.y)<<16);
    f.z = __uint_as_float(((unsigned)u.z)<<16);
    f.w = __uint_as_float(((unsigned)u.w)<<16);
    return f;
}

// ---------------- dtype sniff (inputs f32 vs bf16) ----------------
__global__ void sniff_kernel(const unsigned int* __restrict__ ew, int* __restrict__ flag){
    __shared__ int s;
    if (threadIdx.x == 0) s = 0;
    __syncthreads();
    unsigned int lo = ew[threadIdx.x] & 0xFFFFu;
    if (lo > 0x3F80u) atomicOr(&s, 1);
    __syncthreads();
    if (threadIdx.x == 0) flag[0] = s;   // 1 => inputs are f32
}

// ---------------- weight conversion to f32 scratch ----------------
struct WSeg { const void* src; int base; int n; };
struct WDesc { WSeg seg[14]; };
__global__ void convert_weights(WDesc d, float* __restrict__ dst, const int* __restrict__ flag){
    int isf32 = flag[0];
    int idx = blockIdx.x*256 + threadIdx.x;
    #pragma unroll
    for (int s=0;s<14;s++){
        int off = idx - d.seg[s].base;
        if (off >= 0 && off < d.seg[s].n){
            dst[idx] = loadf(d.seg[s].src, off, isf32);
            return;
        }
    }
}

// ---------------- merged prep: xcvt + repack_whh + repack_wc0 + compose_wc + compose_bias ----------------
// R16: 5 launches -> 1 (all depend only on wcv/flag; R15 proved boundaries cost 10-20us).
// Each sub-job's body is the proven R15 code, selected by blockIdx range.
__global__ __launch_bounds__(256) void prep_kernel(
        const void* __restrict__ x, const int* __restrict__ flag,
        const float* __restrict__ wcv,
        unsigned short* __restrict__ Xb, unsigned short* __restrict__ whb,
        unsigned short* __restrict__ wc0, unsigned short* __restrict__ wpc,
        float* __restrict__ biasc){
    int b = blockIdx.x;
    if (b < XCVT_BLK){                                   // xcvt: Xb[idx]
        long idx = (long)b*256 + threadIdx.x;
        Xb[idx] = f2bfu(loadf(x, idx, flag[0]));
        return;
    }
    b -= XCVT_BLK;
    if (b < 256){                                        // repack_whh
        int idx = b*256 + threadIdx.x;                   // < 65536
        whb[idx] = f2bfu(wcv[OFF_WHH + idx]);
        return;
    }
    b -= 256;
    if (b < 64){                                         // repack_wc0
        int idx = b*256 + threadIdx.x;                   // < 16384
        int k = idx & 127, n = idx >> 7;
        float v = (k < 64) ? 0.5f*wcv[OFF_W0S + n*64 + k] : 0.5f*wcv[OFF_W0D + n*64 + (k-64)];
        wc0[idx] = f2bfu(v);
        return;
    }
    b -= 64;
    if (b < 512){                                        // compose_wc: n = b
        int n = b, k = threadIdx.x;
        const float* wih = wcv + OFF_WIH + n*128;
        const float* w1  = (k < 128) ? (wcv + OFF_W1S + k) : (wcv + OFF_W1D + (k-128));
        float s = 0.f;
        for (int h=0; h<128; h++) s += wih[h] * w1[h*128];
        wpc[n*256 + k] = f2bfu(0.5f * s);
        return;
    }
    b -= 512;
    {                                                    // compose_bias (2 blocks)
        int n = b*256 + threadIdx.x;
        if (n >= 512) return;
        float s = wcv[OFF_BIH+n] + wcv[OFF_BHH+n];
        const float* wih = wcv + OFF_WIH + n*128;
        for (int h=0; h<128; h++) s += wih[h] * 0.5f*(wcv[OFF_B1S+h] + wcv[OFF_B1D+h]);
        biasc[n] = s;
    }
}

// ---------------- histogram: per-(graph, edge-block) LDS partials ----------------
__global__ __launch_bounds__(1024) void hist_kernel(
        const int* __restrict__ ei, const void* __restrict__ ew, const int* __restrict__ flag,
        float* __restrict__ part){
    __shared__ float wdo[N_], wdi[N_];
    __shared__ int   co[N_],  ci[N_];
    int xcd  = blockIdx.x & 7;
    int r2   = blockIdx.x >> 3;
    int g    = xcd*4 + (r2 & 3);
    int b    = r2 >> 2;                     // 0..7
    int tid  = threadIdx.x;
    int isf32 = flag[0];
    for (int i=tid;i<N_;i+=1024){ wdo[i]=0.f; wdi[i]=0.f; co[i]=0; ci[i]=0; }
    __syncthreads();
    const int* eib = ei + g*2*E_;
    int e0 = b*EPB_;
    for (int e=e0+tid; e<e0+EPB_; e+=1024){
        int s = eib[e], d = eib[E_+e];
        float w = loadf(ew, (long)g*E_+e, isf32);
        atomicAdd(&wdo[s], w); atomicAdd(&wdi[d], w);
        atomicAdd(&co[s], 1);  atomicAdd(&ci[d], 1);
    }
    __syncthreads();
    float* Pdo = part + (size_t)(0*G_ + g)*NBLK_*N_ + (size_t)b*N_;
    float* Pdi = part + (size_t)(1*G_ + g)*NBLK_*N_ + (size_t)b*N_;
    int*   Pci = (int*)part + (size_t)(2*G_ + g)*NBLK_*N_ + (size_t)b*N_;
    int*   Pco = (int*)part + (size_t)(3*G_ + g)*NBLK_*N_ + (size_t)b*N_;
    for (int i=tid;i<N_;i+=1024){
        Pdo[i] = wdo[i]; Pdi[i] = wdi[i];
        Pci[i] = ci[i];  Pco[i] = co[i];
    }
}

// ---------------- reduce partials -> deg/cnt; counts -> per-block exclusive prefix ----------------
__global__ __launch_bounds__(256) void reduce_hist(
        float* __restrict__ part,
        float* __restrict__ deg_o, float* __restrict__ deg_i,
        int* __restrict__ cnt_in, int* __restrict__ cnt_out){
    int g = blockIdx.x >> 4;
    int n = (blockIdx.x & 15)*256 + threadIdx.x;
    if (n >= N_) return;
    float* Pdo = part + (size_t)(0*G_ + g)*NBLK_*N_;
    float* Pdi = part + (size_t)(1*G_ + g)*NBLK_*N_;
    int*   Pci = (int*)part + (size_t)(2*G_ + g)*NBLK_*N_;
    int*   Pco = (int*)part + (size_t)(3*G_ + g)*NBLK_*N_;
    float sdo = 0.f, sdi = 0.f;
    int sci = 0, sco = 0;
    #pragma unroll
    for (int b=0;b<NBLK_;b++){
        size_t idx = (size_t)b*N_ + n;
        sdo += Pdo[idx]; sdi += Pdi[idx];
        int vi = Pci[idx], vo = Pco[idx];
        Pci[idx] = sci;  Pco[idx] = sco;   // exclusive prefix for fill
        sci += vi; sco += vo;
    }
    deg_o[g*N_+n] = sdo; deg_i[g*N_+n] = sdi;
    cnt_in[g*N_+n] = sci; cnt_out[g*N_+n] = sco;
}

// ---------------- exclusive scan -> row_ptr ----------------
__global__ __launch_bounds__(256) void scan_kernel(
        const int* __restrict__ cnt_in, const int* __restrict__ cnt_out,
        int* __restrict__ rp_in, int* __restrict__ rp_out){
    __shared__ int part[256], pref[256];
    int g = blockIdx.x & 31, dir = blockIdx.x >> 5;
    const int* cnt = (dir ? cnt_out : cnt_in) + g*N_;
    int* rp  = (dir ? rp_out  : rp_in)  + g*(N_+1);
    int tid = threadIdx.x, base = tid*16;
    int sum = 0;
    for (int i=0;i<16;i++){ int p = base+i; if (p < N_) sum += cnt[p]; }
    part[tid] = sum;
    __syncthreads();
    if (tid == 0){ int run = 0; for (int j=0;j<256;j++){ pref[j] = run; run += part[j]; } }
    __syncthreads();
    int run = pref[tid];
    for (int i=0;i<16;i++){
        int p = base+i;
        if (p < N_){ rp[p] = run; run += cnt[p]; }
    }
    if (tid == 255) rp[N_] = run;
}

// ---------------- fill CSR (no global atomics) ----------------
__global__ __launch_bounds__(1024) void fill_kernel(
        const int* __restrict__ ei, const void* __restrict__ ew,
        const int* __restrict__ flag,
        const float* __restrict__ deg_o, const float* __restrict__ deg_i,
        const int* __restrict__ rp_in, const int* __restrict__ rp_out,
        const float* __restrict__ part,
        int2* __restrict__ csr_in, int2* __restrict__ csr_out){
    __shared__ int lci[N_], lco[N_];
    int xcd  = blockIdx.x & 7;
    int r2   = blockIdx.x >> 3;
    int g    = xcd*4 + (r2 & 3);
    int b    = r2 >> 2;
    int tid  = threadIdx.x;
    int isf32 = flag[0];
    for (int i=tid;i<N_;i+=1024){ lci[i]=0; lco[i]=0; }
    __syncthreads();
    const int* eib = ei + g*2*E_;
    const int* cumI = (const int*)part + (size_t)(2*G_ + g)*NBLK_*N_ + (size_t)b*N_;
    const int* cumO = (const int*)part + (size_t)(3*G_ + g)*NBLK_*N_ + (size_t)b*N_;
    const int* rpi = rp_in  + g*(N_+1);
    const int* rpo = rp_out + g*(N_+1);
    int2* ci = csr_in  + (long)g*E_;
    int2* co = csr_out + (long)g*E_;
    int e0 = b*EPB_;
    for (int e=e0+tid; e<e0+EPB_; e+=1024){
        int s = eib[e], d = eib[E_+e];
        float dout = deg_o[g*N_+s], din = deg_i[g*N_+d];
        float io = dout > 0.f ? rsqrtf(fmaxf(dout, 1e-12f)) : 0.f;
        float ii = din  > 0.f ? rsqrtf(fmaxf(din , 1e-12f)) : 0.f;
        float nrm = loadf(ew, (long)g*E_ + e, isf32) * io * ii;
        int li = atomicAdd(&lci[d], 1);
        ci[rpi[d] + cumI[d] + li] = make_int2(s, __float_as_int(nrm));
        int lo = atomicAdd(&lco[s], 1);
        co[rpo[s] + cumO[s] + lo] = make_int2(d, __float_as_int(nrm));
    }
}

// ---------------- FUSED layer 0: gather(Xb) -> LDS A-tile -> MFMA -> Hb ----------------
__global__ __launch_bounds__(256) void g0fused(
        const int* __restrict__ rp_in, const int* __restrict__ rp_out,
        const int2* __restrict__ csr_in, const int2* __restrict__ csr_out,
        const unsigned short* __restrict__ Xb, const unsigned short* __restrict__ wc0,
        const float* __restrict__ wcv, __hip_bfloat16* __restrict__ Hb){
    __shared__ unsigned short As[64*144];
    int xcd  = blockIdx.x & 7;
    int tile = blockIdx.x >> 3;            // 0..249
    int m0   = (xcd*250 + tile)*64;        // row base in [0, GN)
    int tid  = threadIdx.x;

    int gid = tid >> 3, li = tid & 7;      // 32 groups x 8 lanes
    #pragma unroll
    for (int t=0; t<4; t++){
        int task = t*32 + gid;             // 0..127
        int dir  = task >> 6, r = task & 63;
        int grow = m0 + r;
        int g = grow / N_;  int n = grow - g*N_;
        const int*  rp  = (dir ? rp_out : rp_in) + g*(N_+1);
        const int2* csr = (dir ? csr_out : csr_in) + (long)g*E_;
        int pb = rp[n], pe = rp[n+1];
        int plast = max(pe - 1, 0);
        const unsigned short* base = Xb + (size_t)g*N_*64;
        float acc[8];
        #pragma unroll
        for (int j=0;j<8;j++) acc[j] = 0.f;
        for (int p=pb; p<pe; p+=4){
            float w4[4]; ushort8 v4[4];
            #pragma unroll
            for (int i=0;i<4;i++){
                int pi = p+i;
                int2 ent = csr[min(pi, plast)];
                w4[i] = (pi < pe) ? __int_as_float(ent.y) : 0.f;
                v4[i] = *(const ushort8*)(base + ent.x*64 + li*8);
            }
            #pragma unroll
            for (int i=0;i<4;i++)
                #pragma unroll
                for (int j=0;j<8;j++)
                    acc[j] += w4[i]*bfu2f(v4[i][j]);
        }
        ushort8 o;
        #pragma unroll
        for (int j=0;j<8;j++) o[j] = f2bfu(acc[j]);
        *(ushort8*)(&As[r*144 + dir*64 + li*8]) = o;
    }
    __syncthreads();

    int wave = tid >> 6, lane = tid & 63;
    int quad = lane >> 4, l16 = lane & 15;
    int colb = wave*16 + l16;              // 0..63
    bf16x8 bq[2][4];
    f32x4 acc[2][4];
    #pragma unroll
    for (int s=0;s<2;s++){
        #pragma unroll
        for (int ks=0;ks<4;ks++)
            bq[s][ks] = *(const bf16x8*)(wc0 + (size_t)(colb + s*64)*128 + ks*32 + quad*8);
        #pragma unroll
        for (int t=0;t<4;t++) acc[s][t] = (f32x4){0.f,0.f,0.f,0.f};
    }
    #pragma unroll
    for (int ks=0;ks<4;ks++){
        #pragma unroll
        for (int t=0;t<4;t++){
            bf16x8 a = *(const bf16x8*)(&As[(t*16 + l16)*144 + ks*32 + quad*8]);
            acc[0][t] = __builtin_amdgcn_mfma_f32_16x16x32_bf16(a, bq[0][ks], acc[0][t], 0, 0, 0);
            acc[1][t] = __builtin_amdgcn_mfma_f32_16x16x32_bf16(a, bq[1][ks], acc[1][t], 0, 0, 0);
        }
    }
    #pragma unroll
    for (int s=0;s<2;s++){
        int col = colb + s*64;
        float bias = 0.5f*(wcv[OFF_B0S+col] + wcv[OFF_B0D+col]);
        #pragma unroll
        for (int t=0;t<4;t++)
            #pragma unroll
            for (int r=0;r<4;r++)
                Hb[(size_t)(m0 + t*16 + quad*4 + r)*128 + col] = __float2bfloat16(acc[s][t][r] + bias);
    }
}

// ---------------- FUSED layer 1: gather(Hb) -> LDS A-tile -> MFMA -> gates3 ----------------
// Both halves in ONE 2000-block launch (h0 -> gatesA, h1 -> gatesB aliasing dead Xb).
__global__ __launch_bounds__(512) void ggfused(
        const int* __restrict__ rp_in, const int* __restrict__ rp_out,
        const int2* __restrict__ csr_in, const int2* __restrict__ csr_out,
        const unsigned short* __restrict__ hb,
        const unsigned short* __restrict__ wpc, const float* __restrict__ biasc,
        unsigned short* __restrict__ gatesA, unsigned short* __restrict__ gatesB){
    __shared__ unsigned short As[64*272];
    int xcd   = blockIdx.x & 7;
    int tA    = blockIdx.x >> 3;           // 0..249
    int half  = tA >= 125;
    int tile  = tA - 125*half;             // 0..124
    int m0    = (xcd*125 + tile)*64;       // row base within half
    int gn_base = half*HALF_GN;
    unsigned short* gates = half ? gatesB : gatesA;
    int tid  = threadIdx.x;

    // ---- gather phase ----
    int gid = tid >> 4, li = tid & 15;     // 32 groups x 16 lanes
    #pragma unroll
    for (int t=0; t<4; t++){
        int task = t*32 + gid;             // 0..127
        int dir  = task >> 6, r = task & 63;
        int grow = gn_base + m0 + r;
        int g = grow / N_;  int n = grow - g*N_;
        const int*  rp  = (dir ? rp_out : rp_in) + g*(N_+1);
        const int2* csr = (dir ? csr_out : csr_in) + (long)g*E_;
        int pb = rp[n], pe = rp[n+1];
        int plast = max(pe - 1, 0);
        const unsigned short* base = hb + (size_t)g*N_*128;
        float acc[8];
        #pragma unroll
        for (int j=0;j<8;j++) acc[j] = 0.f;
        for (int p=pb; p<pe; p+=4){
            float w4[4]; ushort8 v4[4];
            #pragma unroll
            for (int i=0;i<4;i++){
                int pi = p+i;
                int2 ent = csr[min(pi, plast)];
                w4[i] = (pi < pe) ? __int_as_float(ent.y) : 0.f;
                v4[i] = *(const ushort8*)(base + ent.x*128 + li*8);
            }
            #pragma unroll
            for (int i=0;i<4;i++)
                #pragma unroll
                for (int j=0;j<8;j++)
                    acc[j] += w4[i]*bfu2f(v4[i][j]);
        }
        ushort8 o;
        #pragma unroll
        for (int j=0;j<8;j++) o[j] = f2bfu(acc[j]);
        *(ushort8*)(&As[r*272 + dir*128 + li*8]) = o;
    }
    __syncthreads();

    // ---- GEMM phase: 64 rows x 512 cols, K=256, 4 col-passes ----
    int w = tid >> 6, lane = tid & 63;
    int quad = lane >> 4, l16 = lane & 15;
    for (int cs=0; cs<4; cs++){
        int col = cs*128 + w*16 + l16;
        bf16x8 bq[8];
        #pragma unroll
        for (int ks=0;ks<8;ks++)
            bq[ks] = *(const bf16x8*)(wpc + (size_t)col*256 + ks*32 + quad*8);
        f32x4 acc[4];
        #pragma unroll
        for (int t=0;t<4;t++) acc[t] = (f32x4){0.f,0.f,0.f,0.f};
        #pragma unroll
        for (int ks=0;ks<8;ks++)
            #pragma unroll
            for (int t=0;t<4;t++){
                bf16x8 a = *(const bf16x8*)(&As[(t*16 + l16)*272 + ks*32 + quad*8]);
                acc[t] = __builtin_amdgcn_mfma_f32_16x16x32_bf16(a, bq[ks], acc[t], 0, 0, 0);
            }
        float bc = biasc[col];
        #pragma unroll
        for (int t=0;t<4;t++)
            #pragma unroll
            for (int r=0;r<4;r++){
                int grow = m0 + t*16 + quad*4 + r;    // gl = m*8 + step (within half)
                gates[(size_t)(grow>>3)*4096 + (size_t)col*8 + (grow&7)] = f2bfu(acc[t][r] + bc);
            }
    }
}

// ---------------- MFMA recurrent LSTM (8 steps) + projection ----------------
// Both halves in ONE 1000-block launch; gates pointer chosen per block.
__global__ __launch_bounds__(512) void lstm7(
        const unsigned short* __restrict__ gatesA, const unsigned short* __restrict__ gatesB,
        const unsigned short* __restrict__ whb,
        const float* __restrict__ wcv, const int* __restrict__ flag,
        void* __restrict__ out){
    __shared__ unsigned short hsh[16*128];
    int tid  = threadIdx.x;
    int w    = tid >> 6;
    int lane = tid & 63;
    int quad = lane >> 4, l15 = lane & 15;
    int mb   = blockIdx.x;               // 0..999
    int half = mb >= 500;
    int mlb  = (mb - 500*half) * 16;     // row base within half
    int m0   = half*HALF_M + mlb;        // global row base (output)
    const unsigned short* gates3 = half ? gatesB : gatesA;
    int isf32 = flag[0];

    ushort8 pg[4][4];
    const unsigned short* gb = gates3 + (size_t)mlb*4096 + (size_t)(w*16 + l15)*8;
    #pragma unroll
    for (int g=0; g<4; g++)
        #pragma unroll
        for (int r=0; r<4; r++)
            pg[g][r] = *(const ushort8*)(gb + (size_t)(quad*4+r)*4096 + (size_t)g*1024);

    bf16x8 bfrag[4][4];
    #pragma unroll
    for (int g=0; g<4; g++)
        #pragma unroll
        for (int kt=0; kt<4; kt++)
            bfrag[g][kt] = *(const bf16x8*)(whb + (size_t)(g*128 + w*16 + l15)*128 + kt*32 + quad*8);

    for (int t=tid; t<16*128; t+=512) hsh[t] = 0;
    f32x4 c = (f32x4){0.f,0.f,0.f,0.f};
    __syncthreads();

    #pragma unroll
    for (int step=0; step<8; step++){
        f32x4 acc[4];
        #pragma unroll
        for (int g=0; g<4; g++)
            #pragma unroll
            for (int r=0; r<4; r++)
                acc[g][r] = bfu2f(pg[g][r][step]);
        #pragma unroll
        for (int kt=0; kt<4; kt++){
            bf16x8 a = *(const bf16x8*)(&hsh[l15*128 + (((kt*4+quad) ^ (l15&15))<<3)]);
            #pragma unroll
            for (int g=0; g<4; g++)
                acc[g] = __builtin_amdgcn_mfma_f32_16x16x32_bf16(a, bfrag[g][kt], acc[g], 0, 0, 0);
        }
        float hnew[4];
        #pragma unroll
        for (int r=0; r<4; r++){
            float gi = sigmf(acc[0][r]), gf = sigmf(acc[1][r]);
            float gg = tanhfast(acc[2][r]), go = sigmf(acc[3][r]);
            float cc = gf*c[r] + gi*gg;
            c[r] = cc;
            hnew[r] = go*tanhfast(cc);
        }
        __syncthreads();
        #pragma unroll
        for (int r=0; r<4; r++){
            int row = quad*4 + r;
            int idx = w*16 + l15;                 // 0..127
            hsh[row*128 + (((idx>>3) ^ (row&15))<<3) + (idx&7)] = f2bfu(hnew[r]);
        }
        __syncthreads();
    }
    int r  = tid >> 5;
    int q0 = (tid & 31) * 2;
    float p0 = wcv[OFF_BP + q0], p1 = wcv[OFF_BP + q0 + 1];
    for (int k4=0;k4<32;k4++){
        float4 hv = cvtbf4(*(const ushort4*)(&hsh[r*128 + (((k4>>1) ^ (r&15))<<3) + (k4&1)*4]));
        float4 w0 = *(const float4*)(wcv + OFF_WP + q0*128 + k4*4);
        float4 w1 = *(const float4*)(wcv + OFF_WP + (q0+1)*128 + k4*4);
        p0 += w0.x*hv.x + w0.y*hv.y + w0.z*hv.z + w0.w*hv.w;
        p1 += w1.x*hv.x + w1.y*hv.y + w1.z*hv.z + w1.w*hv.w;
    }
    long o = (long)(m0+r)*64 + q0;
    if (isf32){ ((float*)out)[o] = p0; ((float*)out)[o+1] = p1; }
    else { ((__hip_bfloat16*)out)[o] = __float2bfloat16(p0);
           ((__hip_bfloat16*)out)[o+1] = __float2bfloat16(p1); }
}

extern "C" void kernel_launch(void* const* d_in, const int* in_sizes, int n_in,
                              void* d_out, int out_size, void* d_ws, size_t ws_size,
                              hipStream_t stream){
    const void* x_seq      = d_in[0];
    const int*  edge_index = (const int*)d_in[1];
    const void* edge_weight= d_in[2];

    float* ws    = (float*)d_ws;
    int*   flag  = (int*)(ws + WS_FLAG);
    float* wcv   = ws + WS_WCV;
    unsigned short* whb = (unsigned short*)(ws + WS_WPH);
    unsigned short* wpc = (unsigned short*)(ws + WS_WPC);
    unsigned short* wc0 = (unsigned short*)(ws + WS_WC0);
    float* biasc = ws + WS_BIASC;
    float* deg_o = ws + WS_DEGO;
    float* deg_i = ws + WS_DEGI;
    int*   cnt_i = (int*)(ws + WS_CNTI);
    int*   cnt_o = (int*)(ws + WS_CNTO);
    int*   rp_i  = (int*)(ws + WS_RPI);
    int*   rp_o  = (int*)(ws + WS_RPO);
    float* partb = ws + WS_PART;
    int2*  csr_i = (int2*)(ws + WS_CSRI);
    int2*  csr_o = (int2*)(ws + WS_CSRO);
    unsigned short* Xb  = (unsigned short*)(ws + WS_X2);
    unsigned short* GT2 = (unsigned short*)(ws + WS_X2);   // aliases Xb (dead after g0fused)
    __hip_bfloat16* Hb = (__hip_bfloat16*)(ws + WS_HB);
    unsigned short* GT = (unsigned short*)(ws + WS_GT);

    sniff_kernel<<<1, 256, 0, stream>>>((const unsigned int*)edge_weight, flag);
    WDesc wd;
    wd.seg[0]  = { d_in[3],  OFF_W0S, 8192  };
    wd.seg[1]  = { d_in[4],  OFF_B0S, 128   };
    wd.seg[2]  = { d_in[5],  OFF_W0D, 8192  };
    wd.seg[3]  = { d_in[6],  OFF_B0D, 128   };
    wd.seg[4]  = { d_in[7],  OFF_W1S, 16384 };
    wd.seg[5]  = { d_in[8],  OFF_B1S, 128   };
    wd.seg[6]  = { d_in[9],  OFF_W1D, 16384 };
    wd.seg[7]  = { d_in[10], OFF_B1D, 128   };
    wd.seg[8]  = { d_in[11], OFF_WIH, 65536 };
    wd.seg[9]  = { d_in[12], OFF_WHH, 65536 };
    wd.seg[10] = { d_in[13], OFF_BIH, 512   };
    wd.seg[11] = { d_in[14], OFF_BHH, 512   };
    wd.seg[12] = { d_in[15], OFF_WP,  8192  };
    wd.seg[13] = { d_in[16], OFF_BP,  64    };
    convert_weights<<<(WCV_TOTAL+255)/256, 256, 0, stream>>>(wd, wcv, flag);

    // merged prep: xcvt + whh/wc0 repack + Wc compose + bias compose (was 5 launches)
    prep_kernel<<<XCVT_BLK + 256 + 64 + 512 + 2, 256, 0, stream>>>(
        x_seq, flag, wcv, Xb, whb, wc0, wpc, biasc);

    hist_kernel<<<G_*NBLK_, 1024, 0, stream>>>(edge_index, edge_weight, flag, partb);
    reduce_hist<<<G_*16, 256, 0, stream>>>(partb, deg_o, deg_i, cnt_i, cnt_o);
    scan_kernel<<<64, 256, 0, stream>>>(cnt_i, cnt_o, rp_i, rp_o);
    fill_kernel<<<G_*NBLK_, 1024, 0, stream>>>(edge_index, edge_weight, flag,
                                               deg_o, deg_i, rp_i, rp_o, partb, csr_i, csr_o);

    // layer 0 fused: gather(Xb) + GEMM -> Hb   (Xb dead afterwards; region reused as GT2)
    g0fused<<<GN_/64, 256, 0, stream>>>(rp_i, rp_o, csr_i, csr_o, Xb, wc0, wcv, Hb);

    // layer 1 fused, both halves in one launch: gather(Hb) + gates GEMM -> GT / GT2
    ggfused<<<GN_/64, 512, 0, stream>>>(rp_i, rp_o, csr_i, csr_o,
                                        (const unsigned short*)Hb, wpc, biasc, GT, GT2);

    // LSTM + projection, both halves in one launch
    lstm7<<<M_/16, 512, 0, stream>>>(GT, GT2, whb, wcv, flag, d_out);
}

// Round 17
// 471.828 us; speedup vs baseline: 1.2873x; 1.0058x over previous
//
#include <hip/hip_runtime.h>
#include <hip/hip_bf16.h>

// Problem constants (B,S,N,F,H,E) = (4,8,4000,64,128,32000)
#define B_  4
#define S_  8
#define N_  4000
#define F_  64
#define H_  128
#define E_  32000
#define G_  (B_*S_)        // 32 graphs
#define GN_ (G_*N_)        // 128000 node rows
#define M_  (B_*N_)        // 16000 LSTM rows
#define GE_ (G_*E_)        // 1,024,000 edges total
#define HALF_GN 64000
#define HALF_M  8000
#define NBLK_   8          // hist/fill blocks per graph
#define EPB_    (E_/NBLK_) // 4000 edges per block
#define XCVT_BLK 32000     // (GN*64)/256

// f32 weight scratch offsets (floats)
#define OFF_W0S 0
#define OFF_B0S 8192
#define OFF_W0D 8320
#define OFF_B0D 16512
#define OFF_W1S 16640
#define OFF_B1S 33024
#define OFF_W1D 33152
#define OFF_B1D 49536
#define OFF_WIH 49664
#define OFF_WHH 115200
#define OFF_BIH 180736
#define OFF_BHH 181248
#define OFF_WP  181760
#define OFF_BP  189952
#define WCV_TOTAL 190016

// workspace layout (float offsets)
#define WS_FLAG   0
#define WS_WCV    16
#define WS_WPH    190032      // Whh bf16 [512][128]: 65536 ushorts
#define WS_WPC    222800      // composed Wc bf16 [512][256]: 131072 ushorts
#define WS_BIASC  288336      // 512 f32
#define WS_DEGO   288848      // deg_o, deg_i, cnt_i, cnt_o contiguous: 4 x 128000 words
#define WS_DEGI   416848
#define WS_CNTI   544848
#define WS_CNTO   672848
#define WS_RPI    800848      // 32*4001
#define WS_RPO    928880
#define WS_CSRI   1312912     // int2 x GE
#define WS_CSRO   3360912
#define WS_X2     5408912     // Xb [GN][64] bf16; after g0fused: GT2 gates3 h1 [8000][512][8]
#define WS_PART   9608912     // hist partials 4 x [32][8][4000] words = 4,096,000 floats
#define WS_HB     21792912    // [GN][128] bf16
#define WS_GT     29984912    // gates3 h0 [8000][512][8] bf16
#define WS_WC0    46368912    // Wc0 bf16 [128][128]: 16384 ushorts = 8192 floats
// end: 46,377,104 floats = 185.5 MiB (proven budget >= 193 MiB)

typedef __attribute__((ext_vector_type(8))) short bf16x8;
typedef __attribute__((ext_vector_type(4))) float f32x4;
typedef __attribute__((ext_vector_type(8))) unsigned short ushort8;

__device__ inline float bfu2f(unsigned short u){ union{unsigned int i; float f;} v; v.i=((unsigned int)u)<<16; return v.f; }
__device__ inline unsigned short f2bfu(float f){ __hip_bfloat16 b = __float2bfloat16(f); return *(unsigned short*)&b; }
__device__ inline float rcpf(float x){ return __builtin_amdgcn_rcpf(x); }
__device__ inline float sigmf(float x){ return rcpf(1.0f + __expf(-x)); }
__device__ inline float tanhfast(float x){ return 1.0f - 2.0f*rcpf(1.0f + __expf(2.0f*x)); }
__device__ inline float loadf(const void* p, long i, int isf32){
    return isf32 ? ((const float*)p)[i]
                 : __bfloat162float(((const __hip_bfloat16*)p)[i]);
}
__device__ inline float4 cvtbf4(ushort4 u){
    float4 f;
    f.x = __uint_as_float(((unsigned)u.x)<<16);
    f.y = __uint_as_float(((unsigned)u.y)<<16);
    f.z = __uint_as_float(((unsigned)u.z)<<16);
    f.w = __uint_as_float(((unsigned)u.w)<<16);
    return f;
}

// ---------------- dtype sniff (inputs f32 vs bf16) ----------------
__global__ void sniff_kernel(const unsigned int* __restrict__ ew, int* __restrict__ flag){
    __shared__ int s;
    if (threadIdx.x == 0) s = 0;
    __syncthreads();
    unsigned int lo = ew[threadIdx.x] & 0xFFFFu;
    if (lo > 0x3F80u) atomicOr(&s, 1);
    __syncthreads();
    if (threadIdx.x == 0) flag[0] = s;   // 1 => inputs are f32
}

// ---------------- weight conversion to f32 scratch ----------------
struct WSeg { const void* src; int base; int n; };
struct WDesc { WSeg seg[14]; };
__global__ void convert_weights(WDesc d, float* __restrict__ dst, const int* __restrict__ flag){
    int isf32 = flag[0];
    int idx = blockIdx.x*256 + threadIdx.x;
    #pragma unroll
    for (int s=0;s<14;s++){
        int off = idx - d.seg[s].base;
        if (off >= 0 && off < d.seg[s].n){
            dst[idx] = loadf(d.seg[s].src, off, isf32);
            return;
        }
    }
}

// ---------------- merged prep: xcvt + repack_whh + repack_wc0 + compose_wc + compose_bias ----------------
__global__ __launch_bounds__(256) void prep_kernel(
        const void* __restrict__ x, const int* __restrict__ flag,
        const float* __restrict__ wcv,
        unsigned short* __restrict__ Xb, unsigned short* __restrict__ whb,
        unsigned short* __restrict__ wc0, unsigned short* __restrict__ wpc,
        float* __restrict__ biasc){
    int b = blockIdx.x;
    if (b < XCVT_BLK){                                   // xcvt: Xb[idx]
        long idx = (long)b*256 + threadIdx.x;
        Xb[idx] = f2bfu(loadf(x, idx, flag[0]));
        return;
    }
    b -= XCVT_BLK;
    if (b < 256){                                        // repack_whh
        int idx = b*256 + threadIdx.x;                   // < 65536
        whb[idx] = f2bfu(wcv[OFF_WHH + idx]);
        return;
    }
    b -= 256;
    if (b < 64){                                         // repack_wc0
        int idx = b*256 + threadIdx.x;                   // < 16384
        int k = idx & 127, n = idx >> 7;
        float v = (k < 64) ? 0.5f*wcv[OFF_W0S + n*64 + k] : 0.5f*wcv[OFF_W0D + n*64 + (k-64)];
        wc0[idx] = f2bfu(v);
        return;
    }
    b -= 64;
    if (b < 512){                                        // compose_wc: n = b
        int n = b, k = threadIdx.x;
        const float* wih = wcv + OFF_WIH + n*128;
        const float* w1  = (k < 128) ? (wcv + OFF_W1S + k) : (wcv + OFF_W1D + (k-128));
        float s = 0.f;
        for (int h=0; h<128; h++) s += wih[h] * w1[h*128];
        wpc[n*256 + k] = f2bfu(0.5f * s);
        return;
    }
    b -= 512;
    {                                                    // compose_bias (2 blocks)
        int n = b*256 + threadIdx.x;
        if (n >= 512) return;
        float s = wcv[OFF_BIH+n] + wcv[OFF_BHH+n];
        const float* wih = wcv + OFF_WIH + n*128;
        for (int h=0; h<128; h++) s += wih[h] * 0.5f*(wcv[OFF_B1S+h] + wcv[OFF_B1D+h]);
        biasc[n] = s;
    }
}

// ---------------- histogram: per-(graph, edge-block) LDS partials ----------------
__global__ __launch_bounds__(1024) void hist_kernel(
        const int* __restrict__ ei, const void* __restrict__ ew, const int* __restrict__ flag,
        float* __restrict__ part){
    __shared__ float wdo[N_], wdi[N_];
    __shared__ int   co[N_],  ci[N_];
    int xcd  = blockIdx.x & 7;
    int r2   = blockIdx.x >> 3;
    int g    = xcd*4 + (r2 & 3);
    int b    = r2 >> 2;                     // 0..7
    int tid  = threadIdx.x;
    int isf32 = flag[0];
    for (int i=tid;i<N_;i+=1024){ wdo[i]=0.f; wdi[i]=0.f; co[i]=0; ci[i]=0; }
    __syncthreads();
    const int* eib = ei + g*2*E_;
    int e0 = b*EPB_;
    for (int e=e0+tid; e<e0+EPB_; e+=1024){
        int s = eib[e], d = eib[E_+e];
        float w = loadf(ew, (long)g*E_+e, isf32);
        atomicAdd(&wdo[s], w); atomicAdd(&wdi[d], w);
        atomicAdd(&co[s], 1);  atomicAdd(&ci[d], 1);
    }
    __syncthreads();
    float* Pdo = part + (size_t)(0*G_ + g)*NBLK_*N_ + (size_t)b*N_;
    float* Pdi = part + (size_t)(1*G_ + g)*NBLK_*N_ + (size_t)b*N_;
    int*   Pci = (int*)part + (size_t)(2*G_ + g)*NBLK_*N_ + (size_t)b*N_;
    int*   Pco = (int*)part + (size_t)(3*G_ + g)*NBLK_*N_ + (size_t)b*N_;
    for (int i=tid;i<N_;i+=1024){
        Pdo[i] = wdo[i]; Pdi[i] = wdi[i];
        Pci[i] = ci[i];  Pco[i] = co[i];
    }
}

// ---------------- reduce partials -> deg/cnt; counts -> per-block exclusive prefix ----------------
__global__ __launch_bounds__(256) void reduce_hist(
        float* __restrict__ part,
        float* __restrict__ deg_o, float* __restrict__ deg_i,
        int* __restrict__ cnt_in, int* __restrict__ cnt_out){
    int g = blockIdx.x >> 4;
    int n = (blockIdx.x & 15)*256 + threadIdx.x;
    if (n >= N_) return;
    float* Pdo = part + (size_t)(0*G_ + g)*NBLK_*N_;
    float* Pdi = part + (size_t)(1*G_ + g)*NBLK_*N_;
    int*   Pci = (int*)part + (size_t)(2*G_ + g)*NBLK_*N_;
    int*   Pco = (int*)part + (size_t)(3*G_ + g)*NBLK_*N_;
    float sdo = 0.f, sdi = 0.f;
    int sci = 0, sco = 0;
    #pragma unroll
    for (int b=0;b<NBLK_;b++){
        size_t idx = (size_t)b*N_ + n;
        sdo += Pdo[idx]; sdi += Pdi[idx];
        int vi = Pci[idx], vo = Pco[idx];
        Pci[idx] = sci;  Pco[idx] = sco;   // exclusive prefix for fill
        sci += vi; sco += vo;
    }
    deg_o[g*N_+n] = sdo; deg_i[g*N_+n] = sdi;
    cnt_in[g*N_+n] = sci; cnt_out[g*N_+n] = sco;
}

// ---------------- exclusive scan -> row_ptr ----------------
__global__ __launch_bounds__(256) void scan_kernel(
        const int* __restrict__ cnt_in, const int* __restrict__ cnt_out,
        int* __restrict__ rp_in, int* __restrict__ rp_out){
    __shared__ int part[256], pref[256];
    int g = blockIdx.x & 31, dir = blockIdx.x >> 5;
    const int* cnt = (dir ? cnt_out : cnt_in) + g*N_;
    int* rp  = (dir ? rp_out  : rp_in)  + g*(N_+1);
    int tid = threadIdx.x, base = tid*16;
    int sum = 0;
    for (int i=0;i<16;i++){ int p = base+i; if (p < N_) sum += cnt[p]; }
    part[tid] = sum;
    __syncthreads();
    if (tid == 0){ int run = 0; for (int j=0;j<256;j++){ pref[j] = run; run += part[j]; } }
    __syncthreads();
    int run = pref[tid];
    for (int i=0;i<16;i++){
        int p = base+i;
        if (p < N_){ rp[p] = run; run += cnt[p]; }
    }
    if (tid == 255) rp[N_] = run;
}

// ---------------- fill CSR (no global atomics) ----------------
__global__ __launch_bounds__(1024) void fill_kernel(
        const int* __restrict__ ei, const void* __restrict__ ew,
        const int* __restrict__ flag,
        const float* __restrict__ deg_o, const float* __restrict__ deg_i,
        const int* __restrict__ rp_in, const int* __restrict__ rp_out,
        const float* __restrict__ part,
        int2* __restrict__ csr_in, int2* __restrict__ csr_out){
    __shared__ int lci[N_], lco[N_];
    int xcd  = blockIdx.x & 7;
    int r2   = blockIdx.x >> 3;
    int g    = xcd*4 + (r2 & 3);
    int b    = r2 >> 2;
    int tid  = threadIdx.x;
    int isf32 = flag[0];
    for (int i=tid;i<N_;i+=1024){ lci[i]=0; lco[i]=0; }
    __syncthreads();
    const int* eib = ei + g*2*E_;
    const int* cumI = (const int*)part + (size_t)(2*G_ + g)*NBLK_*N_ + (size_t)b*N_;
    const int* cumO = (const int*)part + (size_t)(3*G_ + g)*NBLK_*N_ + (size_t)b*N_;
    const int* rpi = rp_in  + g*(N_+1);
    const int* rpo = rp_out + g*(N_+1);
    int2* ci = csr_in  + (long)g*E_;
    int2* co = csr_out + (long)g*E_;
    int e0 = b*EPB_;
    for (int e=e0+tid; e<e0+EPB_; e+=1024){
        int s = eib[e], d = eib[E_+e];
        float dout = deg_o[g*N_+s], din = deg_i[g*N_+d];
        float io = dout > 0.f ? rsqrtf(fmaxf(dout, 1e-12f)) : 0.f;
        float ii = din  > 0.f ? rsqrtf(fmaxf(din , 1e-12f)) : 0.f;
        float nrm = loadf(ew, (long)g*E_ + e, isf32) * io * ii;
        int li = atomicAdd(&lci[d], 1);
        ci[rpi[d] + cumI[d] + li] = make_int2(s, __float_as_int(nrm));
        int lo = atomicAdd(&lco[s], 1);
        co[rpo[s] + cumO[s] + lo] = make_int2(d, __float_as_int(nrm));
    }
}

// ---------------- FUSED layer 0: gather(Xb) -> LDS A-tile -> MFMA -> Hb ----------------
__global__ __launch_bounds__(256) void g0fused(
        const int* __restrict__ rp_in, const int* __restrict__ rp_out,
        const int2* __restrict__ csr_in, const int2* __restrict__ csr_out,
        const unsigned short* __restrict__ Xb, const unsigned short* __restrict__ wc0,
        const float* __restrict__ wcv, __hip_bfloat16* __restrict__ Hb){
    __shared__ unsigned short As[64*144];
    int xcd  = blockIdx.x & 7;
    int tile = blockIdx.x >> 3;            // 0..249
    int m0   = (xcd*250 + tile)*64;        // row base in [0, GN)
    int tid  = threadIdx.x;

    int gid = tid >> 3, li = tid & 7;      // 32 groups x 8 lanes
    #pragma unroll
    for (int t=0; t<4; t++){
        int task = t*32 + gid;             // 0..127
        int dir  = task >> 6, r = task & 63;
        int grow = m0 + r;
        int g = grow / N_;  int n = grow - g*N_;
        const int*  rp  = (dir ? rp_out : rp_in) + g*(N_+1);
        const int2* csr = (dir ? csr_out : csr_in) + (long)g*E_;
        int pb = rp[n], pe = rp[n+1];
        int plast = max(pe - 1, 0);
        const unsigned short* base = Xb + (size_t)g*N_*64;
        float acc[8];
        #pragma unroll
        for (int j=0;j<8;j++) acc[j] = 0.f;
        for (int p=pb; p<pe; p+=4){
            float w4[4]; ushort8 v4[4];
            #pragma unroll
            for (int i=0;i<4;i++){
                int pi = p+i;
                int2 ent = csr[min(pi, plast)];
                w4[i] = (pi < pe) ? __int_as_float(ent.y) : 0.f;
                v4[i] = *(const ushort8*)(base + ent.x*64 + li*8);
            }
            #pragma unroll
            for (int i=0;i<4;i++)
                #pragma unroll
                for (int j=0;j<8;j++)
                    acc[j] += w4[i]*bfu2f(v4[i][j]);
        }
        ushort8 o;
        #pragma unroll
        for (int j=0;j<8;j++) o[j] = f2bfu(acc[j]);
        *(ushort8*)(&As[r*144 + dir*64 + li*8]) = o;
    }
    __syncthreads();

    int wave = tid >> 6, lane = tid & 63;
    int quad = lane >> 4, l16 = lane & 15;
    int colb = wave*16 + l16;              // 0..63
    bf16x8 bq[2][4];
    f32x4 acc[2][4];
    #pragma unroll
    for (int s=0;s<2;s++){
        #pragma unroll
        for (int ks=0;ks<4;ks++)
            bq[s][ks] = *(const bf16x8*)(wc0 + (size_t)(colb + s*64)*128 + ks*32 + quad*8);
        #pragma unroll
        for (int t=0;t<4;t++) acc[s][t] = (f32x4){0.f,0.f,0.f,0.f};
    }
    #pragma unroll
    for (int ks=0;ks<4;ks++){
        #pragma unroll
        for (int t=0;t<4;t++){
            bf16x8 a = *(const bf16x8*)(&As[(t*16 + l16)*144 + ks*32 + quad*8]);
            acc[0][t] = __builtin_amdgcn_mfma_f32_16x16x32_bf16(a, bq[0][ks], acc[0][t], 0, 0, 0);
            acc[1][t] = __builtin_amdgcn_mfma_f32_16x16x32_bf16(a, bq[1][ks], acc[1][t], 0, 0, 0);
        }
    }
    #pragma unroll
    for (int s=0;s<2;s++){
        int col = colb + s*64;
        float bias = 0.5f*(wcv[OFF_B0S+col] + wcv[OFF_B0D+col]);
        #pragma unroll
        for (int t=0;t<4;t++)
            #pragma unroll
            for (int r=0;r<4;r++)
                Hb[(size_t)(m0 + t*16 + quad*4 + r)*128 + col] = __float2bfloat16(acc[s][t][r] + bias);
    }
}

// ---------------- FUSED layer 1: gather(Hb) -> LDS A-tile -> MFMA -> gates3 ----------------
// Both halves in ONE 2000-block launch. R17: epilogue packs the 4 r-values (contiguous
// slots (quad&1)*4..+3 of chunk (grow0>>3)) into one aligned ushort4 store: 64 scalar
// stores/thread -> 16 vector stores.
__global__ __launch_bounds__(512) void ggfused(
        const int* __restrict__ rp_in, const int* __restrict__ rp_out,
        const int2* __restrict__ csr_in, const int2* __restrict__ csr_out,
        const unsigned short* __restrict__ hb,
        const unsigned short* __restrict__ wpc, const float* __restrict__ biasc,
        unsigned short* __restrict__ gatesA, unsigned short* __restrict__ gatesB){
    __shared__ unsigned short As[64*272];
    int xcd   = blockIdx.x & 7;
    int tA    = blockIdx.x >> 3;           // 0..249
    int half  = tA >= 125;
    int tile  = tA - 125*half;             // 0..124
    int m0    = (xcd*125 + tile)*64;       // row base within half
    int gn_base = half*HALF_GN;
    unsigned short* gates = half ? gatesB : gatesA;
    int tid  = threadIdx.x;

    // ---- gather phase ----
    int gid = tid >> 4, li = tid & 15;     // 32 groups x 16 lanes
    #pragma unroll
    for (int t=0; t<4; t++){
        int task = t*32 + gid;             // 0..127
        int dir  = task >> 6, r = task & 63;
        int grow = gn_base + m0 + r;
        int g = grow / N_;  int n = grow - g*N_;
        const int*  rp  = (dir ? rp_out : rp_in) + g*(N_+1);
        const int2* csr = (dir ? csr_out : csr_in) + (long)g*E_;
        int pb = rp[n], pe = rp[n+1];
        int plast = max(pe - 1, 0);
        const unsigned short* base = hb + (size_t)g*N_*128;
        float acc[8];
        #pragma unroll
        for (int j=0;j<8;j++) acc[j] = 0.f;
        for (int p=pb; p<pe; p+=4){
            float w4[4]; ushort8 v4[4];
            #pragma unroll
            for (int i=0;i<4;i++){
                int pi = p+i;
                int2 ent = csr[min(pi, plast)];
                w4[i] = (pi < pe) ? __int_as_float(ent.y) : 0.f;
                v4[i] = *(const ushort8*)(base + ent.x*128 + li*8);
            }
            #pragma unroll
            for (int i=0;i<4;i++)
                #pragma unroll
                for (int j=0;j<8;j++)
                    acc[j] += w4[i]*bfu2f(v4[i][j]);
        }
        ushort8 o;
        #pragma unroll
        for (int j=0;j<8;j++) o[j] = f2bfu(acc[j]);
        *(ushort8*)(&As[r*272 + dir*128 + li*8]) = o;
    }
    __syncthreads();

    // ---- GEMM phase: 64 rows x 512 cols, K=256, 4 col-passes ----
    int w = tid >> 6, lane = tid & 63;
    int quad = lane >> 4, l16 = lane & 15;
    for (int cs=0; cs<4; cs++){
        int col = cs*128 + w*16 + l16;
        bf16x8 bq[8];
        #pragma unroll
        for (int ks=0;ks<8;ks++)
            bq[ks] = *(const bf16x8*)(wpc + (size_t)col*256 + ks*32 + quad*8);
        f32x4 acc[4];
        #pragma unroll
        for (int t=0;t<4;t++) acc[t] = (f32x4){0.f,0.f,0.f,0.f};
        #pragma unroll
        for (int ks=0;ks<8;ks++)
            #pragma unroll
            for (int t=0;t<4;t++){
                bf16x8 a = *(const bf16x8*)(&As[(t*16 + l16)*272 + ks*32 + quad*8]);
                acc[t] = __builtin_amdgcn_mfma_f32_16x16x32_bf16(a, bq[ks], acc[t], 0, 0, 0);
            }
        float bc = biasc[col];
        #pragma unroll
        for (int t=0;t<4;t++){
            int grow0 = m0 + t*16 + quad*4;           // r=0..3 -> contiguous slots
            ushort4 o4;
            o4.x = f2bfu(acc[t][0] + bc);
            o4.y = f2bfu(acc[t][1] + bc);
            o4.z = f2bfu(acc[t][2] + bc);
            o4.w = f2bfu(acc[t][3] + bc);
            *(ushort4*)(&gates[(size_t)(grow0>>3)*4096 + (size_t)col*8 + (grow0&7)]) = o4;
        }
    }
}

// ---------------- MFMA recurrent LSTM (8 steps) + projection ----------------
// Both halves in ONE 1000-block launch; gates pointer chosen per block.
__global__ __launch_bounds__(512) void lstm7(
        const unsigned short* __restrict__ gatesA, const unsigned short* __restrict__ gatesB,
        const unsigned short* __restrict__ whb,
        const float* __restrict__ wcv, const int* __restrict__ flag,
        void* __restrict__ out){
    __shared__ unsigned short hsh[16*128];
    int tid  = threadIdx.x;
    int w    = tid >> 6;
    int lane = tid & 63;
    int quad = lane >> 4, l15 = lane & 15;
    int mb   = blockIdx.x;               // 0..999
    int half = mb >= 500;
    int mlb  = (mb - 500*half) * 16;     // row base within half
    int m0   = half*HALF_M + mlb;        // global row base (output)
    const unsigned short* gates3 = half ? gatesB : gatesA;
    int isf32 = flag[0];

    ushort8 pg[4][4];
    const unsigned short* gb = gates3 + (size_t)mlb*4096 + (size_t)(w*16 + l15)*8;
    #pragma unroll
    for (int g=0; g<4; g++)
        #pragma unroll
        for (int r=0; r<4; r++)
            pg[g][r] = *(const ushort8*)(gb + (size_t)(quad*4+r)*4096 + (size_t)g*1024);

    bf16x8 bfrag[4][4];
    #pragma unroll
    for (int g=0; g<4; g++)
        #pragma unroll
        for (int kt=0; kt<4; kt++)
            bfrag[g][kt] = *(const bf16x8*)(whb + (size_t)(g*128 + w*16 + l15)*128 + kt*32 + quad*8);

    for (int t=tid; t<16*128; t+=512) hsh[t] = 0;
    f32x4 c = (f32x4){0.f,0.f,0.f,0.f};
    __syncthreads();

    #pragma unroll
    for (int step=0; step<8; step++){
        f32x4 acc[4];
        #pragma unroll
        for (int g=0; g<4; g++)
            #pragma unroll
            for (int r=0; r<4; r++)
                acc[g][r] = bfu2f(pg[g][r][step]);
        #pragma unroll
        for (int kt=0; kt<4; kt++){
            bf16x8 a = *(const bf16x8*)(&hsh[l15*128 + (((kt*4+quad) ^ (l15&15))<<3)]);
            #pragma unroll
            for (int g=0; g<4; g++)
                acc[g] = __builtin_amdgcn_mfma_f32_16x16x32_bf16(a, bfrag[g][kt], acc[g], 0, 0, 0);
        }
        float hnew[4];
        #pragma unroll
        for (int r=0; r<4; r++){
            float gi = sigmf(acc[0][r]), gf = sigmf(acc[1][r]);
            float gg = tanhfast(acc[2][r]), go = sigmf(acc[3][r]);
            float cc = gf*c[r] + gi*gg;
            c[r] = cc;
            hnew[r] = go*tanhfast(cc);
        }
        __syncthreads();
        #pragma unroll
        for (int r=0; r<4; r++){
            int row = quad*4 + r;
            int idx = w*16 + l15;                 // 0..127
            hsh[row*128 + (((idx>>3) ^ (row&15))<<3) + (idx&7)] = f2bfu(hnew[r]);
        }
        __syncthreads();
    }
    int r  = tid >> 5;
    int q0 = (tid & 31) * 2;
    float p0 = wcv[OFF_BP + q0], p1 = wcv[OFF_BP + q0 + 1];
    for (int k4=0;k4<32;k4++){
        float4 hv = cvtbf4(*(const ushort4*)(&hsh[r*128 + (((k4>>1) ^ (r&15))<<3) + (k4&1)*4]));
        float4 w0 = *(const float4*)(wcv + OFF_WP + q0*128 + k4*4);
        float4 w1 = *(const float4*)(wcv + OFF_WP + (q0+1)*128 + k4*4);
        p0 += w0.x*hv.x + w0.y*hv.y + w0.z*hv.z + w0.w*hv.w;
        p1 += w1.x*hv.x + w1.y*hv.y + w1.z*hv.z + w1.w*hv.w;
    }
    long o = (long)(m0+r)*64 + q0;
    if (isf32){ ((float*)out)[o] = p0; ((float*)out)[o+1] = p1; }
    else { ((__hip_bfloat16*)out)[o] = __float2bfloat16(p0);
           ((__hip_bfloat16*)out)[o+1] = __float2bfloat16(p1); }
}

extern "C" void kernel_launch(void* const* d_in, const int* in_sizes, int n_in,
                              void* d_out, int out_size, void* d_ws, size_t ws_size,
                              hipStream_t stream){
    const void* x_seq      = d_in[0];
    const int*  edge_index = (const int*)d_in[1];
    const void* edge_weight= d_in[2];

    float* ws    = (float*)d_ws;
    int*   flag  = (int*)(ws + WS_FLAG);
    float* wcv   = ws + WS_WCV;
    unsigned short* whb = (unsigned short*)(ws + WS_WPH);
    unsigned short* wpc = (unsigned short*)(ws + WS_WPC);
    unsigned short* wc0 = (unsigned short*)(ws + WS_WC0);
    float* biasc = ws + WS_BIASC;
    float* deg_o = ws + WS_DEGO;
    float* deg_i = ws + WS_DEGI;
    int*   cnt_i = (int*)(ws + WS_CNTI);
    int*   cnt_o = (int*)(ws + WS_CNTO);
    int*   rp_i  = (int*)(ws + WS_RPI);
    int*   rp_o  = (int*)(ws + WS_RPO);
    float* partb = ws + WS_PART;
    int2*  csr_i = (int2*)(ws + WS_CSRI);
    int2*  csr_o = (int2*)(ws + WS_CSRO);
    unsigned short* Xb  = (unsigned short*)(ws + WS_X2);
    unsigned short* GT2 = (unsigned short*)(ws + WS_X2);   // aliases Xb (dead after g0fused)
    __hip_bfloat16* Hb = (__hip_bfloat16*)(ws + WS_HB);
    unsigned short* GT = (unsigned short*)(ws + WS_GT);

    sniff_kernel<<<1, 256, 0, stream>>>((const unsigned int*)edge_weight, flag);
    WDesc wd;
    wd.seg[0]  = { d_in[3],  OFF_W0S, 8192  };
    wd.seg[1]  = { d_in[4],  OFF_B0S, 128   };
    wd.seg[2]  = { d_in[5],  OFF_W0D, 8192  };
    wd.seg[3]  = { d_in[6],  OFF_B0D, 128   };
    wd.seg[4]  = { d_in[7],  OFF_W1S, 16384 };
    wd.seg[5]  = { d_in[8],  OFF_B1S, 128   };
    wd.seg[6]  = { d_in[9],  OFF_W1D, 16384 };
    wd.seg[7]  = { d_in[10], OFF_B1D, 128   };
    wd.seg[8]  = { d_in[11], OFF_WIH, 65536 };
    wd.seg[9]  = { d_in[12], OFF_WHH, 65536 };
    wd.seg[10] = { d_in[13], OFF_BIH, 512   };
    wd.seg[11] = { d_in[14], OFF_BHH, 512   };
    wd.seg[12] = { d_in[15], OFF_WP,  8192  };
    wd.seg[13] = { d_in[16], OFF_BP,  64    };
    convert_weights<<<(WCV_TOTAL+255)/256, 256, 0, stream>>>(wd, wcv, flag);

    // merged prep: xcvt + whh/wc0 repack + Wc compose + bias compose
    prep_kernel<<<XCVT_BLK + 256 + 64 + 512 + 2, 256, 0, stream>>>(
        x_seq, flag, wcv, Xb, whb, wc0, wpc, biasc);

    hist_kernel<<<G_*NBLK_, 1024, 0, stream>>>(edge_index, edge_weight, flag, partb);
    reduce_hist<<<G_*16, 256, 0, stream>>>(partb, deg_o, deg_i, cnt_i, cnt_o);
    scan_kernel<<<64, 256, 0, stream>>>(cnt_i, cnt_o, rp_i, rp_o);
    fill_kernel<<<G_*NBLK_, 1024, 0, stream>>>(edge_index, edge_weight, flag,
                                               deg_o, deg_i, rp_i, rp_o, partb, csr_i, csr_o);

    // layer 0 fused: gather(Xb) + GEMM -> Hb   (Xb dead afterwards; region reused as GT2)
    g0fused<<<GN_/64, 256, 0, stream>>>(rp_i, rp_o, csr_i, csr_o, Xb, wc0, wcv, Hb);

    // layer 1 fused, both halves in one launch: gather(Hb) + gates GEMM -> GT / GT2
    ggfused<<<GN_/64, 512, 0, stream>>>(rp_i, rp_o, csr_i, csr_o,
                                        (const unsigned short*)Hb, wpc, biasc, GT, GT2);

    // LSTM + projection, both halves in one launch
    lstm7<<<M_/16, 512, 0, stream>>>(GT, GT2, whb, wcv, flag, d_out);
}

// Round 18
// 469.936 us; speedup vs baseline: 1.2925x; 1.0040x over previous
//
#include <hip/hip_runtime.h>
#include <hip/hip_bf16.h>

// Problem constants (B,S,N,F,H,E) = (4,8,4000,64,128,32000)
#define B_  4
#define S_  8
#define N_  4000
#define F_  64
#define H_  128
#define E_  32000
#define G_  (B_*S_)        // 32 graphs
#define GN_ (G_*N_)        // 128000 node rows
#define M_  (B_*N_)        // 16000 LSTM rows
#define GE_ (G_*E_)        // 1,024,000 edges total
#define HALF_GN 64000
#define HALF_M  8000
#define NBLK_   8          // hist/fill blocks per graph
#define EPB_    (E_/NBLK_) // 4000 edges per block
#define XCVT_BLK 32000     // (GN*64)/256

// f32 weight scratch offsets (floats)
#define OFF_W0S 0
#define OFF_B0S 8192
#define OFF_W0D 8320
#define OFF_B0D 16512
#define OFF_W1S 16640
#define OFF_B1S 33024
#define OFF_W1D 33152
#define OFF_B1D 49536
#define OFF_WIH 49664
#define OFF_WHH 115200
#define OFF_BIH 180736
#define OFF_BHH 181248
#define OFF_WP  181760
#define OFF_BP  189952
#define WCV_TOTAL 190016

// workspace layout (float offsets)
#define WS_FLAG   0
#define WS_WCV    16
#define WS_WPH    190032      // Whh bf16 [512][128]: 65536 ushorts
#define WS_WPC    222800      // composed Wc bf16 [512][256]: 131072 ushorts
#define WS_BIASC  288336      // 512 f32
#define WS_DEGO   288848      // deg_o, deg_i, cnt_i, cnt_o contiguous: 4 x 128000 words
#define WS_DEGI   416848
#define WS_CNTI   544848
#define WS_CNTO   672848
#define WS_RPI    800848      // 32*4001
#define WS_RPO    928880
#define WS_CSRI   1312912     // int2 x GE
#define WS_CSRO   3360912
#define WS_X2     5408912     // Xb [GN][64] bf16; after g0fused: GT2 gates3 h1 [8000][512][8]
#define WS_PART   9608912     // hist partials 4 x [32][8][4000] words = 4,096,000 floats
#define WS_HB     21792912    // [GN][128] bf16
#define WS_GT     29984912    // gates3 h0 [8000][512][8] bf16
#define WS_WC0    46368912    // Wc0 bf16 [128][128]: 16384 ushorts = 8192 floats
// end: 46,377,104 floats = 185.5 MiB (proven budget >= 193 MiB)

typedef __attribute__((ext_vector_type(8))) short bf16x8;
typedef __attribute__((ext_vector_type(4))) float f32x4;
typedef __attribute__((ext_vector_type(8))) unsigned short ushort8;

__device__ inline float bfu2f(unsigned short u){ union{unsigned int i; float f;} v; v.i=((unsigned int)u)<<16; return v.f; }
__device__ inline unsigned short f2bfu(float f){ __hip_bfloat16 b = __float2bfloat16(f); return *(unsigned short*)&b; }
__device__ inline float rcpf(float x){ return __builtin_amdgcn_rcpf(x); }
__device__ inline float sigmf(float x){ return rcpf(1.0f + __expf(-x)); }
__device__ inline float tanhfast(float x){ return 1.0f - 2.0f*rcpf(1.0f + __expf(2.0f*x)); }
__device__ inline float loadf(const void* p, long i, int isf32){
    return isf32 ? ((const float*)p)[i]
                 : __bfloat162float(((const __hip_bfloat16*)p)[i]);
}
__device__ inline float4 cvtbf4(ushort4 u){
    float4 f;
    f.x = __uint_as_float(((unsigned)u.x)<<16);
    f.y = __uint_as_float(((unsigned)u.y)<<16);
    f.z = __uint_as_float(((unsigned)u.z)<<16);
    f.w = __uint_as_float(((unsigned)u.w)<<16);
    return f;
}

// ---------------- dtype sniff (inputs f32 vs bf16) ----------------
__global__ void sniff_kernel(const unsigned int* __restrict__ ew, int* __restrict__ flag){
    __shared__ int s;
    if (threadIdx.x == 0) s = 0;
    __syncthreads();
    unsigned int lo = ew[threadIdx.x] & 0xFFFFu;
    if (lo > 0x3F80u) atomicOr(&s, 1);
    __syncthreads();
    if (threadIdx.x == 0) flag[0] = s;   // 1 => inputs are f32
}

// ---------------- weight conversion to f32 scratch ----------------
struct WSeg { const void* src; int base; int n; };
struct WDesc { WSeg seg[14]; };
__global__ void convert_weights(WDesc d, float* __restrict__ dst, const int* __restrict__ flag){
    int isf32 = flag[0];
    int idx = blockIdx.x*256 + threadIdx.x;
    #pragma unroll
    for (int s=0;s<14;s++){
        int off = idx - d.seg[s].base;
        if (off >= 0 && off < d.seg[s].n){
            dst[idx] = loadf(d.seg[s].src, off, isf32);
            return;
        }
    }
}

// ---------------- merged prep: xcvt + repack_whh + repack_wc0 + compose_wc + compose_bias ----------------
__global__ __launch_bounds__(256) void prep_kernel(
        const void* __restrict__ x, const int* __restrict__ flag,
        const float* __restrict__ wcv,
        unsigned short* __restrict__ Xb, unsigned short* __restrict__ whb,
        unsigned short* __restrict__ wc0, unsigned short* __restrict__ wpc,
        float* __restrict__ biasc){
    int b = blockIdx.x;
    if (b < XCVT_BLK){                                   // xcvt: Xb[idx]
        long idx = (long)b*256 + threadIdx.x;
        Xb[idx] = f2bfu(loadf(x, idx, flag[0]));
        return;
    }
    b -= XCVT_BLK;
    if (b < 256){                                        // repack_whh
        int idx = b*256 + threadIdx.x;                   // < 65536
        whb[idx] = f2bfu(wcv[OFF_WHH + idx]);
        return;
    }
    b -= 256;
    if (b < 64){                                         // repack_wc0
        int idx = b*256 + threadIdx.x;                   // < 16384
        int k = idx & 127, n = idx >> 7;
        float v = (k < 64) ? 0.5f*wcv[OFF_W0S + n*64 + k] : 0.5f*wcv[OFF_W0D + n*64 + (k-64)];
        wc0[idx] = f2bfu(v);
        return;
    }
    b -= 64;
    if (b < 512){                                        // compose_wc: n = b
        int n = b, k = threadIdx.x;
        const float* wih = wcv + OFF_WIH + n*128;
        const float* w1  = (k < 128) ? (wcv + OFF_W1S + k) : (wcv + OFF_W1D + (k-128));
        float s = 0.f;
        for (int h=0; h<128; h++) s += wih[h] * w1[h*128];
        wpc[n*256 + k] = f2bfu(0.5f * s);
        return;
    }
    b -= 512;
    {                                                    // compose_bias (2 blocks)
        int n = b*256 + threadIdx.x;
        if (n >= 512) return;
        float s = wcv[OFF_BIH+n] + wcv[OFF_BHH+n];
        const float* wih = wcv + OFF_WIH + n*128;
        for (int h=0; h<128; h++) s += wih[h] * 0.5f*(wcv[OFF_B1S+h] + wcv[OFF_B1D+h]);
        biasc[n] = s;
    }
}

// ---------------- histogram: per-(graph, edge-block) LDS partials ----------------
__global__ __launch_bounds__(1024) void hist_kernel(
        const int* __restrict__ ei, const void* __restrict__ ew, const int* __restrict__ flag,
        float* __restrict__ part){
    __shared__ float wdo[N_], wdi[N_];
    __shared__ int   co[N_],  ci[N_];
    int xcd  = blockIdx.x & 7;
    int r2   = blockIdx.x >> 3;
    int g    = xcd*4 + (r2 & 3);
    int b    = r2 >> 2;                     // 0..7
    int tid  = threadIdx.x;
    int isf32 = flag[0];
    for (int i=tid;i<N_;i+=1024){ wdo[i]=0.f; wdi[i]=0.f; co[i]=0; ci[i]=0; }
    __syncthreads();
    const int* eib = ei + g*2*E_;
    int e0 = b*EPB_;
    for (int e=e0+tid; e<e0+EPB_; e+=1024){
        int s = eib[e], d = eib[E_+e];
        float w = loadf(ew, (long)g*E_+e, isf32);
        atomicAdd(&wdo[s], w); atomicAdd(&wdi[d], w);
        atomicAdd(&co[s], 1);  atomicAdd(&ci[d], 1);
    }
    __syncthreads();
    float* Pdo = part + (size_t)(0*G_ + g)*NBLK_*N_ + (size_t)b*N_;
    float* Pdi = part + (size_t)(1*G_ + g)*NBLK_*N_ + (size_t)b*N_;
    int*   Pci = (int*)part + (size_t)(2*G_ + g)*NBLK_*N_ + (size_t)b*N_;
    int*   Pco = (int*)part + (size_t)(3*G_ + g)*NBLK_*N_ + (size_t)b*N_;
    for (int i=tid;i<N_;i+=1024){
        Pdo[i] = wdo[i]; Pdi[i] = wdi[i];
        Pci[i] = ci[i];  Pco[i] = co[i];
    }
}

// ---------------- reduce partials -> deg/cnt; counts -> per-block exclusive prefix ----------------
__global__ __launch_bounds__(256) void reduce_hist(
        float* __restrict__ part,
        float* __restrict__ deg_o, float* __restrict__ deg_i,
        int* __restrict__ cnt_in, int* __restrict__ cnt_out){
    int g = blockIdx.x >> 4;
    int n = (blockIdx.x & 15)*256 + threadIdx.x;
    if (n >= N_) return;
    float* Pdo = part + (size_t)(0*G_ + g)*NBLK_*N_;
    float* Pdi = part + (size_t)(1*G_ + g)*NBLK_*N_;
    int*   Pci = (int*)part + (size_t)(2*G_ + g)*NBLK_*N_;
    int*   Pco = (int*)part + (size_t)(3*G_ + g)*NBLK_*N_;
    float sdo = 0.f, sdi = 0.f;
    int sci = 0, sco = 0;
    #pragma unroll
    for (int b=0;b<NBLK_;b++){
        size_t idx = (size_t)b*N_ + n;
        sdo += Pdo[idx]; sdi += Pdi[idx];
        int vi = Pci[idx], vo = Pco[idx];
        Pci[idx] = sci;  Pco[idx] = sco;   // exclusive prefix for fill
        sci += vi; sco += vo;
    }
    deg_o[g*N_+n] = sdo; deg_i[g*N_+n] = sdi;
    cnt_in[g*N_+n] = sci; cnt_out[g*N_+n] = sco;
}

// ---------------- exclusive scan -> row_ptr ----------------
__global__ __launch_bounds__(256) void scan_kernel(
        const int* __restrict__ cnt_in, const int* __restrict__ cnt_out,
        int* __restrict__ rp_in, int* __restrict__ rp_out){
    __shared__ int part[256], pref[256];
    int g = blockIdx.x & 31, dir = blockIdx.x >> 5;
    const int* cnt = (dir ? cnt_out : cnt_in) + g*N_;
    int* rp  = (dir ? rp_out  : rp_in)  + g*(N_+1);
    int tid = threadIdx.x, base = tid*16;
    int sum = 0;
    for (int i=0;i<16;i++){ int p = base+i; if (p < N_) sum += cnt[p]; }
    part[tid] = sum;
    __syncthreads();
    if (tid == 0){ int run = 0; for (int j=0;j<256;j++){ pref[j] = run; run += part[j]; } }
    __syncthreads();
    int run = pref[tid];
    for (int i=0;i<16;i++){
        int p = base+i;
        if (p < N_){ rp[p] = run; run += cnt[p]; }
    }
    if (tid == 255) rp[N_] = run;
}

// ---------------- fill CSR (no global atomics) ----------------
__global__ __launch_bounds__(1024) void fill_kernel(
        const int* __restrict__ ei, const void* __restrict__ ew,
        const int* __restrict__ flag,
        const float* __restrict__ deg_o, const float* __restrict__ deg_i,
        const int* __restrict__ rp_in, const int* __restrict__ rp_out,
        const float* __restrict__ part,
        int2* __restrict__ csr_in, int2* __restrict__ csr_out){
    __shared__ int lci[N_], lco[N_];
    int xcd  = blockIdx.x & 7;
    int r2   = blockIdx.x >> 3;
    int g    = xcd*4 + (r2 & 3);
    int b    = r2 >> 2;
    int tid  = threadIdx.x;
    int isf32 = flag[0];
    for (int i=tid;i<N_;i+=1024){ lci[i]=0; lco[i]=0; }
    __syncthreads();
    const int* eib = ei + g*2*E_;
    const int* cumI = (const int*)part + (size_t)(2*G_ + g)*NBLK_*N_ + (size_t)b*N_;
    const int* cumO = (const int*)part + (size_t)(3*G_ + g)*NBLK_*N_ + (size_t)b*N_;
    const int* rpi = rp_in  + g*(N_+1);
    const int* rpo = rp_out + g*(N_+1);
    int2* ci = csr_in  + (long)g*E_;
    int2* co = csr_out + (long)g*E_;
    int e0 = b*EPB_;
    for (int e=e0+tid; e<e0+EPB_; e+=1024){
        int s = eib[e], d = eib[E_+e];
        float dout = deg_o[g*N_+s], din = deg_i[g*N_+d];
        float io = dout > 0.f ? rsqrtf(fmaxf(dout, 1e-12f)) : 0.f;
        float ii = din  > 0.f ? rsqrtf(fmaxf(din , 1e-12f)) : 0.f;
        float nrm = loadf(ew, (long)g*E_ + e, isf32) * io * ii;
        int li = atomicAdd(&lci[d], 1);
        ci[rpi[d] + cumI[d] + li] = make_int2(s, __float_as_int(nrm));
        int lo = atomicAdd(&lco[s], 1);
        co[rpo[s] + cumO[s] + lo] = make_int2(d, __float_as_int(nrm));
    }
}

// ---------------- FUSED layer 0: gather(Xb) -> LDS A-tile -> MFMA -> Hb ----------------
// R18: 2-deep csr-entry pipeline — next round's entries load while current round's
// row loads + FMAs run (round cost ~max(lat) instead of csr_lat+row_lat).
__global__ __launch_bounds__(256) void g0fused(
        const int* __restrict__ rp_in, const int* __restrict__ rp_out,
        const int2* __restrict__ csr_in, const int2* __restrict__ csr_out,
        const unsigned short* __restrict__ Xb, const unsigned short* __restrict__ wc0,
        const float* __restrict__ wcv, __hip_bfloat16* __restrict__ Hb){
    __shared__ unsigned short As[64*144];
    int xcd  = blockIdx.x & 7;
    int tile = blockIdx.x >> 3;            // 0..249
    int m0   = (xcd*250 + tile)*64;        // row base in [0, GN)
    int tid  = threadIdx.x;

    int gid = tid >> 3, li = tid & 7;      // 32 groups x 8 lanes
    #pragma unroll
    for (int t=0; t<4; t++){
        int task = t*32 + gid;             // 0..127
        int dir  = task >> 6, r = task & 63;
        int grow = m0 + r;
        int g = grow / N_;  int n = grow - g*N_;
        const int*  rp  = (dir ? rp_out : rp_in) + g*(N_+1);
        const int2* csr = (dir ? csr_out : csr_in) + (long)g*E_;
        int pb = rp[n], pe = rp[n+1];
        int plast = max(pe - 1, 0);
        const unsigned short* base = Xb + (size_t)g*N_*64;
        float acc[8];
        #pragma unroll
        for (int j=0;j<8;j++) acc[j] = 0.f;
        int2 e4[4];
        #pragma unroll
        for (int i=0;i<4;i++) e4[i] = csr[min(pb+i, plast)];
        for (int p=pb; p<pe; p+=4){
            int2 n4[4];
            #pragma unroll
            for (int i=0;i<4;i++) n4[i] = csr[min(p+4+i, plast)];
            float w4[4]; ushort8 v4[4];
            #pragma unroll
            for (int i=0;i<4;i++){
                w4[i] = (p+i < pe) ? __int_as_float(e4[i].y) : 0.f;
                v4[i] = *(const ushort8*)(base + e4[i].x*64 + li*8);
            }
            #pragma unroll
            for (int i=0;i<4;i++)
                #pragma unroll
                for (int j=0;j<8;j++)
                    acc[j] += w4[i]*bfu2f(v4[i][j]);
            #pragma unroll
            for (int i=0;i<4;i++) e4[i] = n4[i];
        }
        ushort8 o;
        #pragma unroll
        for (int j=0;j<8;j++) o[j] = f2bfu(acc[j]);
        *(ushort8*)(&As[r*144 + dir*64 + li*8]) = o;
    }
    __syncthreads();

    int wave = tid >> 6, lane = tid & 63;
    int quad = lane >> 4, l16 = lane & 15;
    int colb = wave*16 + l16;              // 0..63
    bf16x8 bq[2][4];
    f32x4 acc[2][4];
    #pragma unroll
    for (int s=0;s<2;s++){
        #pragma unroll
        for (int ks=0;ks<4;ks++)
            bq[s][ks] = *(const bf16x8*)(wc0 + (size_t)(colb + s*64)*128 + ks*32 + quad*8);
        #pragma unroll
        for (int t=0;t<4;t++) acc[s][t] = (f32x4){0.f,0.f,0.f,0.f};
    }
    #pragma unroll
    for (int ks=0;ks<4;ks++){
        #pragma unroll
        for (int t=0;t<4;t++){
            bf16x8 a = *(const bf16x8*)(&As[(t*16 + l16)*144 + ks*32 + quad*8]);
            acc[0][t] = __builtin_amdgcn_mfma_f32_16x16x32_bf16(a, bq[0][ks], acc[0][t], 0, 0, 0);
            acc[1][t] = __builtin_amdgcn_mfma_f32_16x16x32_bf16(a, bq[1][ks], acc[1][t], 0, 0, 0);
        }
    }
    #pragma unroll
    for (int s=0;s<2;s++){
        int col = colb + s*64;
        float bias = 0.5f*(wcv[OFF_B0S+col] + wcv[OFF_B0D+col]);
        #pragma unroll
        for (int t=0;t<4;t++)
            #pragma unroll
            for (int r=0;r<4;r++)
                Hb[(size_t)(m0 + t*16 + quad*4 + r)*128 + col] = __float2bfloat16(acc[s][t][r] + bias);
    }
}

// ---------------- FUSED layer 1: gather(Hb) -> LDS A-tile -> MFMA -> gates3 ----------------
// Both halves in ONE 2000-block launch. R18: 2-deep csr pipeline in gather; R17
// vectorized ushort4 epilogue kept.
__global__ __launch_bounds__(512) void ggfused(
        const int* __restrict__ rp_in, const int* __restrict__ rp_out,
        const int2* __restrict__ csr_in, const int2* __restrict__ csr_out,
        const unsigned short* __restrict__ hb,
        const unsigned short* __restrict__ wpc, const float* __restrict__ biasc,
        unsigned short* __restrict__ gatesA, unsigned short* __restrict__ gatesB){
    __shared__ unsigned short As[64*272];
    int xcd   = blockIdx.x & 7;
    int tA    = blockIdx.x >> 3;           // 0..249
    int half  = tA >= 125;
    int tile  = tA - 125*half;             // 0..124
    int m0    = (xcd*125 + tile)*64;       // row base within half
    int gn_base = half*HALF_GN;
    unsigned short* gates = half ? gatesB : gatesA;
    int tid  = threadIdx.x;

    // ---- gather phase ----
    int gid = tid >> 4, li = tid & 15;     // 32 groups x 16 lanes
    #pragma unroll
    for (int t=0; t<4; t++){
        int task = t*32 + gid;             // 0..127
        int dir  = task >> 6, r = task & 63;
        int grow = gn_base + m0 + r;
        int g = grow / N_;  int n = grow - g*N_;
        const int*  rp  = (dir ? rp_out : rp_in) + g*(N_+1);
        const int2* csr = (dir ? csr_out : csr_in) + (long)g*E_;
        int pb = rp[n], pe = rp[n+1];
        int plast = max(pe - 1, 0);
        const unsigned short* base = hb + (size_t)g*N_*128;
        float acc[8];
        #pragma unroll
        for (int j=0;j<8;j++) acc[j] = 0.f;
        int2 e4[4];
        #pragma unroll
        for (int i=0;i<4;i++) e4[i] = csr[min(pb+i, plast)];
        for (int p=pb; p<pe; p+=4){
            int2 n4[4];
            #pragma unroll
            for (int i=0;i<4;i++) n4[i] = csr[min(p+4+i, plast)];
            float w4[4]; ushort8 v4[4];
            #pragma unroll
            for (int i=0;i<4;i++){
                w4[i] = (p+i < pe) ? __int_as_float(e4[i].y) : 0.f;
                v4[i] = *(const ushort8*)(base + e4[i].x*128 + li*8);
            }
            #pragma unroll
            for (int i=0;i<4;i++)
                #pragma unroll
                for (int j=0;j<8;j++)
                    acc[j] += w4[i]*bfu2f(v4[i][j]);
            #pragma unroll
            for (int i=0;i<4;i++) e4[i] = n4[i];
        }
        ushort8 o;
        #pragma unroll
        for (int j=0;j<8;j++) o[j] = f2bfu(acc[j]);
        *(ushort8*)(&As[r*272 + dir*128 + li*8]) = o;
    }
    __syncthreads();

    // ---- GEMM phase: 64 rows x 512 cols, K=256, 4 col-passes ----
    int w = tid >> 6, lane = tid & 63;
    int quad = lane >> 4, l16 = lane & 15;
    for (int cs=0; cs<4; cs++){
        int col = cs*128 + w*16 + l16;
        bf16x8 bq[8];
        #pragma unroll
        for (int ks=0;ks<8;ks++)
            bq[ks] = *(const bf16x8*)(wpc + (size_t)col*256 + ks*32 + quad*8);
        f32x4 acc[4];
        #pragma unroll
        for (int t=0;t<4;t++) acc[t] = (f32x4){0.f,0.f,0.f,0.f};
        #pragma unroll
        for (int ks=0;ks<8;ks++)
            #pragma unroll
            for (int t=0;t<4;t++){
                bf16x8 a = *(const bf16x8*)(&As[(t*16 + l16)*272 + ks*32 + quad*8]);
                acc[t] = __builtin_amdgcn_mfma_f32_16x16x32_bf16(a, bq[ks], acc[t], 0, 0, 0);
            }
        float bc = biasc[col];
        #pragma unroll
        for (int t=0;t<4;t++){
            int grow0 = m0 + t*16 + quad*4;           // r=0..3 -> contiguous slots
            ushort4 o4;
            o4.x = f2bfu(acc[t][0] + bc);
            o4.y = f2bfu(acc[t][1] + bc);
            o4.z = f2bfu(acc[t][2] + bc);
            o4.w = f2bfu(acc[t][3] + bc);
            *(ushort4*)(&gates[(size_t)(grow0>>3)*4096 + (size_t)col*8 + (grow0&7)]) = o4;
        }
    }
}

// ---------------- MFMA recurrent LSTM (8 steps) + projection ----------------
// Both halves in ONE 1000-block launch; gates pointer chosen per block.
__global__ __launch_bounds__(512) void lstm7(
        const unsigned short* __restrict__ gatesA, const unsigned short* __restrict__ gatesB,
        const unsigned short* __restrict__ whb,
        const float* __restrict__ wcv, const int* __restrict__ flag,
        void* __restrict__ out){
    __shared__ unsigned short hsh[16*128];
    int tid  = threadIdx.x;
    int w    = tid >> 6;
    int lane = tid & 63;
    int quad = lane >> 4, l15 = lane & 15;
    int mb   = blockIdx.x;               // 0..999
    int half = mb >= 500;
    int mlb  = (mb - 500*half) * 16;     // row base within half
    int m0   = half*HALF_M + mlb;        // global row base (output)
    const unsigned short* gates3 = half ? gatesB : gatesA;
    int isf32 = flag[0];

    ushort8 pg[4][4];
    const unsigned short* gb = gates3 + (size_t)mlb*4096 + (size_t)(w*16 + l15)*8;
    #pragma unroll
    for (int g=0; g<4; g++)
        #pragma unroll
        for (int r=0; r<4; r++)
            pg[g][r] = *(const ushort8*)(gb + (size_t)(quad*4+r)*4096 + (size_t)g*1024);

    bf16x8 bfrag[4][4];
    #pragma unroll
    for (int g=0; g<4; g++)
        #pragma unroll
        for (int kt=0; kt<4; kt++)
            bfrag[g][kt] = *(const bf16x8*)(whb + (size_t)(g*128 + w*16 + l15)*128 + kt*32 + quad*8);

    for (int t=tid; t<16*128; t+=512) hsh[t] = 0;
    f32x4 c = (f32x4){0.f,0.f,0.f,0.f};
    __syncthreads();

    #pragma unroll
    for (int step=0; step<8; step++){
        f32x4 acc[4];
        #pragma unroll
        for (int g=0; g<4; g++)
            #pragma unroll
            for (int r=0; r<4; r++)
                acc[g][r] = bfu2f(pg[g][r][step]);
        #pragma unroll
        for (int kt=0; kt<4; kt++){
            bf16x8 a = *(const bf16x8*)(&hsh[l15*128 + (((kt*4+quad) ^ (l15&15))<<3)]);
            #pragma unroll
            for (int g=0; g<4; g++)
                acc[g] = __builtin_amdgcn_mfma_f32_16x16x32_bf16(a, bfrag[g][kt], acc[g], 0, 0, 0);
        }
        float hnew[4];
        #pragma unroll
        for (int r=0; r<4; r++){
            float gi = sigmf(acc[0][r]), gf = sigmf(acc[1][r]);
            float gg = tanhfast(acc[2][r]), go = sigmf(acc[3][r]);
            float cc = gf*c[r] + gi*gg;
            c[r] = cc;
            hnew[r] = go*tanhfast(cc);
        }
        __syncthreads();
        #pragma unroll
        for (int r=0; r<4; r++){
            int row = quad*4 + r;
            int idx = w*16 + l15;                 // 0..127
            hsh[row*128 + (((idx>>3) ^ (row&15))<<3) + (idx&7)] = f2bfu(hnew[r]);
        }
        __syncthreads();
    }
    int r  = tid >> 5;
    int q0 = (tid & 31) * 2;
    float p0 = wcv[OFF_BP + q0], p1 = wcv[OFF_BP + q0 + 1];
    for (int k4=0;k4<32;k4++){
        float4 hv = cvtbf4(*(const ushort4*)(&hsh[r*128 + (((k4>>1) ^ (r&15))<<3) + (k4&1)*4]));
        float4 w0 = *(const float4*)(wcv + OFF_WP + q0*128 + k4*4);
        float4 w1 = *(const float4*)(wcv + OFF_WP + (q0+1)*128 + k4*4);
        p0 += w0.x*hv.x + w0.y*hv.y + w0.z*hv.z + w0.w*hv.w;
        p1 += w1.x*hv.x + w1.y*hv.y + w1.z*hv.z + w1.w*hv.w;
    }
    long o = (long)(m0+r)*64 + q0;
    if (isf32){ ((float*)out)[o] = p0; ((float*)out)[o+1] = p1; }
    else { ((__hip_bfloat16*)out)[o] = __float2bfloat16(p0);
           ((__hip_bfloat16*)out)[o+1] = __float2bfloat16(p1); }
}

extern "C" void kernel_launch(void* const* d_in, const int* in_sizes, int n_in,
                              void* d_out, int out_size, void* d_ws, size_t ws_size,
                              hipStream_t stream){
    const void* x_seq      = d_in[0];
    const int*  edge_index = (const int*)d_in[1];
    const void* edge_weight= d_in[2];

    float* ws    = (float*)d_ws;
    int*   flag  = (int*)(ws + WS_FLAG);
    float* wcv   = ws + WS_WCV;
    unsigned short* whb = (unsigned short*)(ws + WS_WPH);
    unsigned short* wpc = (unsigned short*)(ws + WS_WPC);
    unsigned short* wc0 = (unsigned short*)(ws + WS_WC0);
    float* biasc = ws + WS_BIASC;
    float* deg_o = ws + WS_DEGO;
    float* deg_i = ws + WS_DEGI;
    int*   cnt_i = (int*)(ws + WS_CNTI);
    int*   cnt_o = (int*)(ws + WS_CNTO);
    int*   rp_i  = (int*)(ws + WS_RPI);
    int*   rp_o  = (int*)(ws + WS_RPO);
    float* partb = ws + WS_PART;
    int2*  csr_i = (int2*)(ws + WS_CSRI);
    int2*  csr_o = (int2*)(ws + WS_CSRO);
    unsigned short* Xb  = (unsigned short*)(ws + WS_X2);
    unsigned short* GT2 = (unsigned short*)(ws + WS_X2);   // aliases Xb (dead after g0fused)
    __hip_bfloat16* Hb = (__hip_bfloat16*)(ws + WS_HB);
    unsigned short* GT = (unsigned short*)(ws + WS_GT);

    sniff_kernel<<<1, 256, 0, stream>>>((const unsigned int*)edge_weight, flag);
    WDesc wd;
    wd.seg[0]  = { d_in[3],  OFF_W0S, 8192  };
    wd.seg[1]  = { d_in[4],  OFF_B0S, 128   };
    wd.seg[2]  = { d_in[5],  OFF_W0D, 8192  };
    wd.seg[3]  = { d_in[6],  OFF_B0D, 128   };
    wd.seg[4]  = { d_in[7],  OFF_W1S, 16384 };
    wd.seg[5]  = { d_in[8],  OFF_B1S, 128   };
    wd.seg[6]  = { d_in[9],  OFF_W1D, 16384 };
    wd.seg[7]  = { d_in[10], OFF_B1D, 128   };
    wd.seg[8]  = { d_in[11], OFF_WIH, 65536 };
    wd.seg[9]  = { d_in[12], OFF_WHH, 65536 };
    wd.seg[10] = { d_in[13], OFF_BIH, 512   };
    wd.seg[11] = { d_in[14], OFF_BHH, 512   };
    wd.seg[12] = { d_in[15], OFF_WP,  8192  };
    wd.seg[13] = { d_in[16], OFF_BP,  64    };
    convert_weights<<<(WCV_TOTAL+255)/256, 256, 0, stream>>>(wd, wcv, flag);

    // merged prep: xcvt + whh/wc0 repack + Wc compose + bias compose
    prep_kernel<<<XCVT_BLK + 256 + 64 + 512 + 2, 256, 0, stream>>>(
        x_seq, flag, wcv, Xb, whb, wc0, wpc, biasc);

    hist_kernel<<<G_*NBLK_, 1024, 0, stream>>>(edge_index, edge_weight, flag, partb);
    reduce_hist<<<G_*16, 256, 0, stream>>>(partb, deg_o, deg_i, cnt_i, cnt_o);
    scan_kernel<<<64, 256, 0, stream>>>(cnt_i, cnt_o, rp_i, rp_o);
    fill_kernel<<<G_*NBLK_, 1024, 0, stream>>>(edge_index, edge_weight, flag,
                                               deg_o, deg_i, rp_i, rp_o, partb, csr_i, csr_o);

    // layer 0 fused: gather(Xb) + GEMM -> Hb   (Xb dead afterwards; region reused as GT2)
    g0fused<<<GN_/64, 256, 0, stream>>>(rp_i, rp_o, csr_i, csr_o, Xb, wc0, wcv, Hb);

    // layer 1 fused, both halves in one launch: gather(Hb) + gates GEMM -> GT / GT2
    ggfused<<<GN_/64, 512, 0, stream>>>(rp_i, rp_o, csr_i, csr_o,
                                        (const unsigned short*)Hb, wpc, biasc, GT, GT2);

    // LSTM + projection, both halves in one launch
    lstm7<<<M_/16, 512, 0, stream>>>(GT, GT2, whb, wcv, flag, d_out);
}